// Round 11
// baseline (459.908 us; speedup 1.0000x reference)
//
#include <hip/hip_runtime.h>

// BondAwareEGNN fused layer — round 16.
//
// Round-15 post-mortem: operand swap WIN (172.5->161us, VALU 41.5->36,
// WRITE 140->125.6 = r13's mild spill also gone, regs 64+32 -> 56+32).
// msg still latency-limited: occ 40% (4 waves/SIMD; ~88 regs total is
// 3 over the 6-wave threshold of ~85).
//
// Round-16: msg __launch_bounds__(256,4) -> (256,6). One-token change;
// if the allocator shaves 88->85 without spilling, occ 40->~60% on a
// latency-bound kernel. Spill guard: WRITE must stay ~125.6MB, FETCH
// ~152MB; WRITE>140 or VGPR_Count=32 => revert. Node unchanged.

#define H      128
#define NA     20000
#define NB     60000
#define NBATCH 8
#define ADJ_CAP 32

typedef __bf16 bf16;
typedef __bf16 bf16x4 __attribute__((ext_vector_type(4)));
typedef __bf16 bf16x8 __attribute__((ext_vector_type(8)));
typedef float  f32x4  __attribute__((ext_vector_type(4)));

__device__ __forceinline__ float silu_f(float v) {
  float e = __expf(-v);
  return v * __builtin_amdgcn_rcpf(1.0f + e);  // 1-ulp rcp; inf -> 0 ok
}

// XOR-swizzled index into a [R][128] bf16 tile. Row stride 256B (bank
// neutral); 16B chunk index XOR'd with row&7 rotates banks. Bijective per
// row; 8-element chunks stay contiguous so bf16x8/bf16x4 ops still work.
__device__ __forceinline__ int tswz(int row, int col) {
  return (row << 7) + (((((col) >> 3) ^ (row & 7)) << 3) | (col & 7));
}

__global__ void cast_h(const float* __restrict__ src, bf16* __restrict__ dst) {
  int i = blockIdx.x * 256 + threadIdx.x;  // one float4 per thread
  float4 v = *(const float4*)(src + (size_t)i * 4);
  bf16x4 t = {(bf16)v.x, (bf16)v.y, (bf16)v.z, (bf16)v.w};
  *(bf16x4*)(dst + (size_t)i * 4) = t;
}

// fp32 KxN(128) row-major -> bf16 fragment-linear (8 bf16 per lane-frag).
__device__ __forceinline__ void pack_one(const float* __restrict__ src,
                                         bf16* __restrict__ dst, int K,
                                         int i) {
  int k = i >> 7, n = i & 127;
  int nt = n >> 4, ks = k >> 5;
  int lane = (((k >> 3) & 3) << 4) | (n & 15);
  int j = k & 7;
  int KS = K >> 5;
  dst[((((nt * KS + ks) * 64) + lane) << 3) + j] = (bf16)src[i];
}

// all five weight packs in one dispatch (ranges: 32K,16K,32K,16K,16K)
__global__ void pack_all(const float* __restrict__ Wm1,
                         const float* __restrict__ Wm2,
                         const float* __restrict__ Wn1,
                         const float* __restrict__ Wn2,
                         const float* __restrict__ Wc1,
                         bf16* __restrict__ W1p, bf16* __restrict__ W2p,
                         bf16* __restrict__ Wn1p, bf16* __restrict__ Wn2p,
                         bf16* __restrict__ Wc1p) {
  int i = blockIdx.x * 256 + threadIdx.x;
  if (i < 32768)       pack_one(Wm1, W1p, 256, i);
  else if (i < 49152)  pack_one(Wm2, W2p, 128, i - 32768);
  else if (i < 81920)  pack_one(Wn1, Wn1p, 256, i - 49152);
  else if (i < 98304)  pack_one(Wn2, Wn2p, 128, i - 81920);
  else if (i < 114688) pack_one(Wc1, Wc1p, 128, i - 98304);
}

// ---------------- adjacency build (fixed-capacity slots) ----------------
__global__ void build_adj2(const int* __restrict__ bonds,
                           int* __restrict__ degI, int* __restrict__ adj2) {
  int e = blockIdx.x * 256 + threadIdx.x;
  if (e >= NB) return;
  int s = bonds[2 * e], d = bonds[2 * e + 1];
  int p = atomicAdd(&degI[s], 1);
  if (p < ADJ_CAP) adj2[s * ADJ_CAP + p] = (e << 1);        // src: sign -
  p = atomicAdd(&degI[d], 1);
  if (p < ADJ_CAP) adj2[d * ADJ_CAP + p] = (e << 1) | 1;    // dst: sign +
}

// ---------------- message kernel (M=32 x N=64 per wave, swapped MFMA) ----
__global__ __launch_bounds__(256, 6) void msg_kernel(
    const bf16* __restrict__ hb, const float* __restrict__ x,
    const int* __restrict__ bonds,
    const bf16* __restrict__ W1p, const float* __restrict__ bm1,
    const bf16* __restrict__ W2p, const float* __restrict__ bm2,
    const float* __restrict__ w1c,   // Wm1 row 256 (dist row), fp32[128]
    const bf16* __restrict__ Wc1p, const float* __restrict__ bc1,
    const float* __restrict__ Wc2,
    bf16* __restrict__ msgOut, float* __restrict__ updv) {
  // [64][128] swizzled tile: T after layer-1, messages after layer-2.
  __shared__ __align__(16) bf16 Tbuf[64 * 128];
  __shared__ __align__(16) float cds[64 * 3];
  __shared__ __align__(16) float dists[64];
  __shared__ __align__(16) float bm1s[128], bm2s[128], w1cs[128];
  __shared__ __align__(16) float bc1s[128], wc2s[128];
  __shared__ float cwpart[2][64];

  const int tid = threadIdx.x, blk = blockIdx.x;

  if (tid < 64) {
    int Rg = blk * 64 + tid;
    int bond = Rg >> 3, batch = Rg & 7;
    int s = bonds[2 * bond], dn = bonds[2 * bond + 1];
    const float* xs = x + (size_t)(batch * NA + s) * 3;
    const float* xd = x + (size_t)(batch * NA + dn) * 3;
    float c0 = xd[0] - xs[0], c1 = xd[1] - xs[1], c2 = xd[2] - xs[2];
    cds[tid * 3 + 0] = c0; cds[tid * 3 + 1] = c1; cds[tid * 3 + 2] = c2;
    dists[tid] = sqrtf(c0 * c0 + c1 * c1 + c2 * c2);
  }
  if (tid < 128) {
    bm1s[tid] = bm1[tid]; bm2s[tid] = bm2[tid]; w1cs[tid] = w1c[tid];
    bc1s[tid] = bc1[tid]; wc2s[tid] = Wc2[tid];
  }
  __syncthreads();

  const int lane = tid & 63;
  const int quad = lane >> 4, l16 = lane & 15;
  const int wave = tid >> 6;
  const int rowBase = (wave >> 1) * 32;    // 2 row-groups of 32
  const int colG = wave & 1;               // 2 col-groups of 64
  const int colBase = colG * 64;
  const bf16x8* W1v = (const bf16x8*)W1p;
  const bf16x8* W2v = (const bf16x8*)W2p;
  const bf16x8* Wc1v = (const bf16x8*)Wc1p;

  // per-lane A-row metadata, two row sets (rowBase+l16, rowBase+16+l16)
  const int row0 = rowBase + l16, row1 = row0 + 16;
  const int Rg0 = blk * 64 + row0;
  const int bn0 = Rg0 >> 3, bat0 = Rg0 & 7;
  const bf16* hs0 = hb + (size_t)(bat0 * NA + bonds[2 * bn0]) * H;
  const bf16* hd0 = hb + (size_t)(bat0 * NA + bonds[2 * bn0 + 1]) * H;
  const int Rg1 = Rg0 + 16;
  const int bn1_ = Rg1 >> 3, bat1 = Rg1 & 7;
  const bf16* hs1 = hb + (size_t)(bat1 * NA + bonds[2 * bn1_]) * H;
  const bf16* hd1 = hb + (size_t)(bat1 * NA + bonds[2 * bn1_ + 1]) * H;
  const float dist0 = dists[row0], dist1 = dists[row1];

  f32x4 acc0[4], acc1[4];
#pragma unroll
  for (int nt = 0; nt < 4; nt++) {
    acc0[nt] = (f32x4){0.f, 0.f, 0.f, 0.f};
    acc1[nt] = (f32x4){0.f, 0.f, 0.f, 0.f};
  }

  // ---- layer 1: K = 256; swapped operands -> regs = 4 consecutive cols --
#pragma unroll
  for (int ks = 0; ks < 4; ks++) {
    bf16x8 a0 = *(const bf16x8*)(hs0 + ks * 32 + quad * 8);
    bf16x8 a1 = *(const bf16x8*)(hs1 + ks * 32 + quad * 8);
#pragma unroll
    for (int nt = 0; nt < 4; nt++) {
      bf16x8 b = W1v[((colG * 4 + nt) * 8 + ks) * 64 + lane];
      acc0[nt] = __builtin_amdgcn_mfma_f32_16x16x32_bf16(b, a0, acc0[nt], 0, 0, 0);
      acc1[nt] = __builtin_amdgcn_mfma_f32_16x16x32_bf16(b, a1, acc1[nt], 0, 0, 0);
    }
  }
#pragma unroll
  for (int ks = 4; ks < 8; ks++) {
    bf16x8 a0 = *(const bf16x8*)(hd0 + (ks - 4) * 32 + quad * 8);
    bf16x8 a1 = *(const bf16x8*)(hd1 + (ks - 4) * 32 + quad * 8);
#pragma unroll
    for (int nt = 0; nt < 4; nt++) {
      bf16x8 b = W1v[((colG * 4 + nt) * 8 + ks) * 64 + lane];
      acc0[nt] = __builtin_amdgcn_mfma_f32_16x16x32_bf16(b, a0, acc0[nt], 0, 0, 0);
      acc1[nt] = __builtin_amdgcn_mfma_f32_16x16x32_bf16(b, a1, acc1[nt], 0, 0, 0);
    }
  }
  // t1 epilogue -> Tbuf: one bf16x4 8B write per tile per row-set
#pragma unroll
  for (int nt = 0; nt < 4; nt++) {
    int col = colBase + nt * 16 + quad * 4;
    f32x4 bb = *(const f32x4*)&bm1s[col];
    f32x4 wc = *(const f32x4*)&w1cs[col];
    bf16x4 o0, o1;
#pragma unroll
    for (int reg = 0; reg < 4; reg++) {
      o0[reg] = (bf16)silu_f(acc0[nt][reg] + bb[reg] + dist0 * wc[reg]);
      o1[reg] = (bf16)silu_f(acc1[nt][reg] + bb[reg] + dist1 * wc[reg]);
    }
    *(bf16x4*)&Tbuf[tswz(row0, col)] = o0;
    *(bf16x4*)&Tbuf[tswz(row1, col)] = o1;
  }
  __syncthreads();   // T complete

  // ---- layer 2: K = 128 -> messages ----
#pragma unroll
  for (int nt = 0; nt < 4; nt++) {
    acc0[nt] = (f32x4){0.f, 0.f, 0.f, 0.f};
    acc1[nt] = (f32x4){0.f, 0.f, 0.f, 0.f};
  }
#pragma unroll
  for (int ks = 0; ks < 4; ks++) {
    bf16x8 a0 = *(const bf16x8*)&Tbuf[tswz(row0, ks * 32 + quad * 8)];
    bf16x8 a1 = *(const bf16x8*)&Tbuf[tswz(row1, ks * 32 + quad * 8)];
#pragma unroll
    for (int nt = 0; nt < 4; nt++) {
      bf16x8 b = W2v[((colG * 4 + nt) * 4 + ks) * 64 + lane];
      acc0[nt] = __builtin_amdgcn_mfma_f32_16x16x32_bf16(b, a0, acc0[nt], 0, 0, 0);
      acc1[nt] = __builtin_amdgcn_mfma_f32_16x16x32_bf16(b, a1, acc1[nt], 0, 0, 0);
    }
  }
  __syncthreads();   // all T reads done; safe to overwrite
#pragma unroll
  for (int nt = 0; nt < 4; nt++) {
    int col = colBase + nt * 16 + quad * 4;
    f32x4 bb = *(const f32x4*)&bm2s[col];
    bf16x4 o0, o1;
#pragma unroll
    for (int reg = 0; reg < 4; reg++) {
      o0[reg] = (bf16)silu_f(acc0[nt][reg] + bb[reg]);
      o1[reg] = (bf16)silu_f(acc1[nt][reg] + bb[reg]);
    }
    *(bf16x4*)&Tbuf[tswz(row0, col)] = o0;
    *(bf16x4*)&Tbuf[tswz(row1, col)] = o1;
  }
  __syncthreads();   // messages complete

  // ---- coord head ----
#pragma unroll
  for (int nt = 0; nt < 4; nt++) {
    acc0[nt] = (f32x4){0.f, 0.f, 0.f, 0.f};
    acc1[nt] = (f32x4){0.f, 0.f, 0.f, 0.f};
  }
#pragma unroll
  for (int ks = 0; ks < 4; ks++) {
    bf16x8 a0 = *(const bf16x8*)&Tbuf[tswz(row0, ks * 32 + quad * 8)];
    bf16x8 a1 = *(const bf16x8*)&Tbuf[tswz(row1, ks * 32 + quad * 8)];
#pragma unroll
    for (int nt = 0; nt < 4; nt++) {
      bf16x8 b = Wc1v[((colG * 4 + nt) * 4 + ks) * 64 + lane];
      acc0[nt] = __builtin_amdgcn_mfma_f32_16x16x32_bf16(b, a0, acc0[nt], 0, 0, 0);
      acc1[nt] = __builtin_amdgcn_mfma_f32_16x16x32_bf16(b, a1, acc1[nt], 0, 0, 0);
    }
  }

  // copy 64 message rows to global (4 x 16B chunks per thread, coalesced)
#pragma unroll
  for (int i = 0; i < 4; i++) {
    int item = i * 256 + tid;
    int row = item >> 4, cg = item & 15;
    *(bf16x8*)&msgOut[(size_t)(blk * 64 + row) * H + cg * 8] =
        *(const bf16x8*)&Tbuf[tswz(row, cg * 8)];
  }

  // lane-local sum over this lane's 16 cols, then reduce across quads
  float s0 = 0.f, s1 = 0.f;
#pragma unroll
  for (int nt = 0; nt < 4; nt++) {
    int col = colBase + nt * 16 + quad * 4;
    f32x4 bb = *(const f32x4*)&bc1s[col];
    f32x4 w2 = *(const f32x4*)&wc2s[col];
#pragma unroll
    for (int reg = 0; reg < 4; reg++) {
      s0 += silu_f(acc0[nt][reg] + bb[reg]) * w2[reg];
      s1 += silu_f(acc1[nt][reg] + bb[reg]) * w2[reg];
    }
  }
  s0 += __shfl_xor(s0, 16); s0 += __shfl_xor(s0, 32);
  s1 += __shfl_xor(s1, 16); s1 += __shfl_xor(s1, 32);
  if (quad == 0) {
    cwpart[colG][row0] = s0;
    cwpart[colG][row1] = s1;
  }
  __syncthreads();   // both col-halves' partials in
  if (colG == 0 && quad == 0) {
#pragma unroll
    for (int rs = 0; rs < 2; rs++) {
      int row = rs ? row1 : row0;
      size_t Rg = (size_t)blk * 64 + row;
      float cw = cwpart[0][row] + cwpart[1][row];
      float inv = 1.0f / (dists[row] + 1e-8f);
#pragma unroll
      for (int c = 0; c < 3; c++)
        updv[Rg * 3 + c] = cds[row * 3 + c] * inv * cw;
    }
  }
}

// ---------------- node kernel (2-phase; swapped MFMA phase 2) -------------
__global__ __launch_bounds__(256, 6) void node_kernel(
    const float* __restrict__ h, const bf16* __restrict__ hb,
    const bf16* __restrict__ msg, const float* __restrict__ updv,
    const int* __restrict__ degI, const int* __restrict__ adj2,
    const bf16* __restrict__ Wn1p, const float* __restrict__ bn1,
    const bf16* __restrict__ Wn2p, const float* __restrict__ bn2,
    const float* __restrict__ x,
    float* __restrict__ hout, float* __restrict__ xout) {
  __shared__ __align__(16) bf16 Abuf[32 * 128];
  __shared__ __align__(16) bf16 Tbuf[32 * 128];

  const int tid = threadIdx.x, blk = blockIdx.x;

  // ---- phase 1: gather ----
  {
    const int row = tid >> 3, c8 = tid & 7;       // 32 rows x 8 chunks
    const int Rg = blk * 32 + row;                // batch*NA + atom
    const int atomA = Rg % NA, batA = Rg / NA;
    int deg = degI[atomA];
    if (deg > ADJ_CAP) deg = ADJ_CAP;
    const int* ap = adj2 + atomA * ADJ_CAP;
    float a16[16];
#pragma unroll
    for (int t = 0; t < 16; t++) a16[t] = 0.f;
    float sx = 0.f, sy = 0.f, sz = 0.f;
    int j = 0;
    for (; j + 4 <= deg; j += 4) {
      int4 e4 = *(const int4*)&ap[j];   // one load, 4 entries
      const bf16* m0 = msg + ((size_t)(e4.x >> 1) * 8 + batA) * H + c8 * 16;
      const bf16* m1 = msg + ((size_t)(e4.y >> 1) * 8 + batA) * H + c8 * 16;
      const bf16* m2 = msg + ((size_t)(e4.z >> 1) * 8 + batA) * H + c8 * 16;
      const bf16* m3 = msg + ((size_t)(e4.w >> 1) * 8 + batA) * H + c8 * 16;
      bf16x8 v0 = *(const bf16x8*)(m0), v1 = *(const bf16x8*)(m0 + 8);
      bf16x8 u0 = *(const bf16x8*)(m1), u1 = *(const bf16x8*)(m1 + 8);
      bf16x8 p0 = *(const bf16x8*)(m2), p1 = *(const bf16x8*)(m2 + 8);
      bf16x8 q0 = *(const bf16x8*)(m3), q1 = *(const bf16x8*)(m3 + 8);
      if (c8 == 0) {
        float sg0 = (e4.x & 1) ? 1.0f : -1.0f;
        float sg1 = (e4.y & 1) ? 1.0f : -1.0f;
        float sg2 = (e4.z & 1) ? 1.0f : -1.0f;
        float sg3 = (e4.w & 1) ? 1.0f : -1.0f;
        const float* uv0 = updv + ((size_t)(e4.x >> 1) * 8 + batA) * 3;
        const float* uv1 = updv + ((size_t)(e4.y >> 1) * 8 + batA) * 3;
        const float* uv2 = updv + ((size_t)(e4.z >> 1) * 8 + batA) * 3;
        const float* uv3 = updv + ((size_t)(e4.w >> 1) * 8 + batA) * 3;
        sx += sg0 * uv0[0] + sg1 * uv1[0] + sg2 * uv2[0] + sg3 * uv3[0];
        sy += sg0 * uv0[1] + sg1 * uv1[1] + sg2 * uv2[1] + sg3 * uv3[1];
        sz += sg0 * uv0[2] + sg1 * uv1[2] + sg2 * uv2[2] + sg3 * uv3[2];
      }
#pragma unroll
      for (int t = 0; t < 8; t++) {
        a16[t]     += ((float)v0[t] + (float)u0[t]) + ((float)p0[t] + (float)q0[t]);
        a16[8 + t] += ((float)v1[t] + (float)u1[t]) + ((float)p1[t] + (float)q1[t]);
      }
    }
    for (; j < deg; j++) {
      int ent0 = ap[j];
      const bf16* m0 = msg + ((size_t)(ent0 >> 1) * 8 + batA) * H + c8 * 16;
      bf16x8 v0 = *(const bf16x8*)(m0);
      bf16x8 v1 = *(const bf16x8*)(m0 + 8);
      if (c8 == 0) {
        float sg0 = (ent0 & 1) ? 1.0f : -1.0f;
        const float* uv0 = updv + ((size_t)(ent0 >> 1) * 8 + batA) * 3;
        sx += sg0 * uv0[0]; sy += sg0 * uv0[1]; sz += sg0 * uv0[2];
      }
#pragma unroll
      for (int t = 0; t < 8; t++) {
        a16[t]     += (float)v0[t];
        a16[8 + t] += (float)v1[t];
      }
    }
    if (c8 == 0) {   // x finalize
      float cnt = deg < 1 ? 1.0f : (float)deg;
      float inv = 1.0f / cnt;
      size_t o = (size_t)Rg * 3;
      xout[o + 0] = x[o + 0] + sx * inv;
      xout[o + 1] = x[o + 1] + sy * inv;
      xout[o + 2] = x[o + 2] + sz * inv;
    }
    bf16x8 w0, w1;
#pragma unroll
    for (int t = 0; t < 8; t++) { w0[t] = (bf16)a16[t]; w1[t] = (bf16)a16[8 + t]; }
    *(bf16x8*)&Abuf[tswz(row, c8 * 16)]     = w0;
    *(bf16x8*)&Abuf[tswz(row, c8 * 16 + 8)] = w1;
  }
  __syncthreads();   // agg tile ready

  // ---- phase 2: node MLP, N-split, swapped MFMA ----
  const int lane = tid & 63, wave = tid >> 6;
  const int quad = lane >> 4, l16 = lane & 15;
  const int rowG = (wave >> 1) * 16, colG = wave & 1, colBase = colG * 64;
  const int rowL = rowG + l16;
  const size_t RgA = (size_t)blk * 32 + rowL;
  const bf16* hrow = hb + RgA * H;
  const bf16x8* W1v = (const bf16x8*)Wn1p;
  const bf16x8* W2v = (const bf16x8*)Wn2p;

  f32x4 acc[4];
#pragma unroll
  for (int nt = 0; nt < 4; nt++) acc[nt] = (f32x4){0.f, 0.f, 0.f, 0.f};

  // layer-1 first half: h (bf16) register-direct from global
#pragma unroll
  for (int ks = 0; ks < 4; ks++) {
    bf16x8 a = *(const bf16x8*)(hrow + ks * 32 + quad * 8);
#pragma unroll
    for (int nt = 0; nt < 4; nt++) {
      bf16x8 b = W1v[((colG * 4 + nt) * 8 + ks) * 64 + lane];
      acc[nt] = __builtin_amdgcn_mfma_f32_16x16x32_bf16(b, a, acc[nt], 0, 0, 0);
    }
  }
  // layer-1 second half: aggregated from LDS
#pragma unroll
  for (int ks2 = 0; ks2 < 4; ks2++) {
    bf16x8 a = *(const bf16x8*)&Abuf[tswz(rowL, ks2 * 32 + quad * 8)];
#pragma unroll
    for (int nt = 0; nt < 4; nt++) {
      bf16x8 b = W1v[((colG * 4 + nt) * 8 + 4 + ks2) * 64 + lane];
      acc[nt] = __builtin_amdgcn_mfma_f32_16x16x32_bf16(b, a, acc[nt], 0, 0, 0);
    }
  }
#pragma unroll
  for (int nt = 0; nt < 4; nt++) {
    int col = colBase + nt * 16 + quad * 4;
    f32x4 bb = *(const f32x4*)&bn1[col];
    bf16x4 o;
#pragma unroll
    for (int reg = 0; reg < 4; reg++)
      o[reg] = (bf16)silu_f(acc[nt][reg] + bb[reg]);
    *(bf16x4*)&Tbuf[tswz(rowL, col)] = o;
  }
  __syncthreads();   // T complete (both col halves)

#pragma unroll
  for (int nt = 0; nt < 4; nt++) acc[nt] = (f32x4){0.f, 0.f, 0.f, 0.f};
#pragma unroll
  for (int ks = 0; ks < 4; ks++) {
    bf16x8 a = *(const bf16x8*)&Tbuf[tswz(rowL, ks * 32 + quad * 8)];
#pragma unroll
    for (int nt = 0; nt < 4; nt++) {
      bf16x8 b = W2v[((colG * 4 + nt) * 4 + ks) * 64 + lane];
      acc[nt] = __builtin_amdgcn_mfma_f32_16x16x32_bf16(b, a, acc[nt], 0, 0, 0);
    }
  }
#pragma unroll
  for (int nt = 0; nt < 4; nt++) {
    int col = colBase + nt * 16 + quad * 4;
    f32x4 bb = *(const f32x4*)&bn2[col];
    f32x4 hv = *(const f32x4*)&h[RgA * H + col];
    f32x4 o;
#pragma unroll
    for (int reg = 0; reg < 4; reg++)
      o[reg] = hv[reg] + acc[nt][reg] + bb[reg];
    *(f32x4*)&hout[RgA * H + col] = o;
  }
}

extern "C" void kernel_launch(void* const* d_in, const int* in_sizes, int n_in,
                              void* d_out, int out_size, void* d_ws,
                              size_t ws_size, hipStream_t stream) {
  const float* h    = (const float*)d_in[0];
  const float* x    = (const float*)d_in[1];
  const int*  bonds = (const int*)d_in[2];
  const float* Wm1  = (const float*)d_in[3];
  const float* bm1  = (const float*)d_in[4];
  const float* Wm2  = (const float*)d_in[5];
  const float* bm2  = (const float*)d_in[6];
  const float* Wn1  = (const float*)d_in[7];
  const float* bn1  = (const float*)d_in[8];
  const float* Wn2  = (const float*)d_in[9];
  const float* bn2  = (const float*)d_in[10];
  const float* Wc1  = (const float*)d_in[11];
  const float* bc1  = (const float*)d_in[12];
  const float* Wc2  = (const float*)d_in[13];

  float* out  = (float*)d_out;
  float* hout = out;
  float* xout = out + (size_t)NBATCH * NA * H;

  char* ws = (char*)d_ws;
  // layout (bytes): NEED = 172,553,216 < 173,080,576 proven available.
  const size_t OFF_DEG  = 0;                        // NA int = 80,000
  const size_t OFF_W1   = 163840;                   // 65,536
  const size_t OFF_W2   = OFF_W1 + 65536;           // 32,768
  const size_t OFF_WN1  = OFF_W2 + 32768;           // 65,536
  const size_t OFF_WN2  = OFF_WN1 + 65536;          // 32,768
  const size_t OFF_WC1  = OFF_WN2 + 32768;          // 32,768 (ends 393,216)
  const size_t OFF_ADJ2 = 393216;                   // NA*32 int = 2,560,000
  const size_t OFF_UPDV = 2953216;                  // NB*8*3 f32 = 5,760,000
  const size_t OFF_HB   = 8713216;                  // 160000*128 bf16 = 40,960,000
  const size_t OFF_MSG  = 49673216;                 // NB*8*128 bf16 = 122,880,000

  int*   degI = (int*)(ws + OFF_DEG);
  bf16*  W1p  = (bf16*)(ws + OFF_W1);
  bf16*  W2p  = (bf16*)(ws + OFF_W2);
  bf16*  Wn1p = (bf16*)(ws + OFF_WN1);
  bf16*  Wn2p = (bf16*)(ws + OFF_WN2);
  bf16*  Wc1p = (bf16*)(ws + OFF_WC1);
  int*   adj2 = (int*)(ws + OFF_ADJ2);
  float* updv = (float*)(ws + OFF_UPDV);
  bf16*  hb   = (bf16*)(ws + OFF_HB);
  bf16*  msgB = (bf16*)(ws + OFF_MSG);

  (void)hipMemsetAsync(degI, 0, NA * sizeof(int), stream);

  cast_h<<<NBATCH * NA * H / 1024, 256, 0, stream>>>(h, hb);
  pack_all<<<448, 256, 0, stream>>>(Wm1, Wm2, Wn1, Wn2, Wc1,
                                    W1p, W2p, Wn1p, Wn2p, Wc1p);
  build_adj2<<<(NB + 255) / 256, 256, 0, stream>>>(bonds, degI, adj2);

  msg_kernel<<<NB * NBATCH / 64, 256, 0, stream>>>(
      hb, x, bonds, W1p, bm1, W2p, bm2, Wm1 + 256 * H, Wc1p, bc1, Wc2,
      msgB, updv);
  node_kernel<<<NBATCH * NA / 32, 256, 0, stream>>>(
      h, hb, msgB, updv, degI, adj2, Wn1p, bn1, Wn2p, bn2, x,
      hout, xout);
}

// Round 12
// 433.016 us; speedup vs baseline: 1.0621x; 1.0621x over previous
//
#include <hip/hip_runtime.h>

// BondAwareEGNN fused layer — round 17.
//
// Round-16 post-mortem: (256,6) spilled (WRITE 125.6->207MB, VGPR 56->40)
// — occ 40->62 but dur 161->171. msg occupancy ladder CLOSED: 4 waves +
// no spill is the local optimum (r6/r9/r16 squeeze and r8 expand all lose).
//
// Round-17: msg reverted to (256,4) = r15 exact (161us). Node gets msg's
// proven r13 win: phase-2 M=32xN=64 per wave (2 acc sets share every W
// fragment, 1:2 B:MFMA). Block 32->64 rows (grid 2500); phase-1 gather
// 4 threads/row x 64B, 2-way unroll (8 loads in flight, ~84 regs; a32
// dies before phase-2's ~88). Both under (256,4)'s 128 cap — msg's
// proven no-spill budget. Guard: msg WRITE ~125.6MB; node must NOT
// appear in top-5 above msg.

#define H      128
#define NA     20000
#define NB     60000
#define NBATCH 8
#define ADJ_CAP 32

typedef __bf16 bf16;
typedef __bf16 bf16x4 __attribute__((ext_vector_type(4)));
typedef __bf16 bf16x8 __attribute__((ext_vector_type(8)));
typedef float  f32x4  __attribute__((ext_vector_type(4)));

__device__ __forceinline__ float silu_f(float v) {
  float e = __expf(-v);
  return v * __builtin_amdgcn_rcpf(1.0f + e);  // 1-ulp rcp; inf -> 0 ok
}

// XOR-swizzled index into a [R][128] bf16 tile. Row stride 256B (bank
// neutral); 16B chunk index XOR'd with row&7 rotates banks. Bijective per
// row; 8-element chunks stay contiguous so bf16x8/bf16x4 ops still work.
__device__ __forceinline__ int tswz(int row, int col) {
  return (row << 7) + (((((col) >> 3) ^ (row & 7)) << 3) | (col & 7));
}

__global__ void cast_h(const float* __restrict__ src, bf16* __restrict__ dst) {
  int i = blockIdx.x * 256 + threadIdx.x;  // one float4 per thread
  float4 v = *(const float4*)(src + (size_t)i * 4);
  bf16x4 t = {(bf16)v.x, (bf16)v.y, (bf16)v.z, (bf16)v.w};
  *(bf16x4*)(dst + (size_t)i * 4) = t;
}

// fp32 KxN(128) row-major -> bf16 fragment-linear (8 bf16 per lane-frag).
__device__ __forceinline__ void pack_one(const float* __restrict__ src,
                                         bf16* __restrict__ dst, int K,
                                         int i) {
  int k = i >> 7, n = i & 127;
  int nt = n >> 4, ks = k >> 5;
  int lane = (((k >> 3) & 3) << 4) | (n & 15);
  int j = k & 7;
  int KS = K >> 5;
  dst[((((nt * KS + ks) * 64) + lane) << 3) + j] = (bf16)src[i];
}

// all five weight packs in one dispatch (ranges: 32K,16K,32K,16K,16K)
__global__ void pack_all(const float* __restrict__ Wm1,
                         const float* __restrict__ Wm2,
                         const float* __restrict__ Wn1,
                         const float* __restrict__ Wn2,
                         const float* __restrict__ Wc1,
                         bf16* __restrict__ W1p, bf16* __restrict__ W2p,
                         bf16* __restrict__ Wn1p, bf16* __restrict__ Wn2p,
                         bf16* __restrict__ Wc1p) {
  int i = blockIdx.x * 256 + threadIdx.x;
  if (i < 32768)       pack_one(Wm1, W1p, 256, i);
  else if (i < 49152)  pack_one(Wm2, W2p, 128, i - 32768);
  else if (i < 81920)  pack_one(Wn1, Wn1p, 256, i - 49152);
  else if (i < 98304)  pack_one(Wn2, Wn2p, 128, i - 81920);
  else if (i < 114688) pack_one(Wc1, Wc1p, 128, i - 98304);
}

// ---------------- adjacency build (fixed-capacity slots) ----------------
__global__ void build_adj2(const int* __restrict__ bonds,
                           int* __restrict__ degI, int* __restrict__ adj2) {
  int e = blockIdx.x * 256 + threadIdx.x;
  if (e >= NB) return;
  int s = bonds[2 * e], d = bonds[2 * e + 1];
  int p = atomicAdd(&degI[s], 1);
  if (p < ADJ_CAP) adj2[s * ADJ_CAP + p] = (e << 1);        // src: sign -
  p = atomicAdd(&degI[d], 1);
  if (p < ADJ_CAP) adj2[d * ADJ_CAP + p] = (e << 1) | 1;    // dst: sign +
}

// ---------------- message kernel (M=32 x N=64 per wave, swapped MFMA) ----
__global__ __launch_bounds__(256, 4) void msg_kernel(
    const bf16* __restrict__ hb, const float* __restrict__ x,
    const int* __restrict__ bonds,
    const bf16* __restrict__ W1p, const float* __restrict__ bm1,
    const bf16* __restrict__ W2p, const float* __restrict__ bm2,
    const float* __restrict__ w1c,   // Wm1 row 256 (dist row), fp32[128]
    const bf16* __restrict__ Wc1p, const float* __restrict__ bc1,
    const float* __restrict__ Wc2,
    bf16* __restrict__ msgOut, float* __restrict__ updv) {
  // [64][128] swizzled tile: T after layer-1, messages after layer-2.
  __shared__ __align__(16) bf16 Tbuf[64 * 128];
  __shared__ __align__(16) float cds[64 * 3];
  __shared__ __align__(16) float dists[64];
  __shared__ __align__(16) float bm1s[128], bm2s[128], w1cs[128];
  __shared__ __align__(16) float bc1s[128], wc2s[128];
  __shared__ float cwpart[2][64];

  const int tid = threadIdx.x, blk = blockIdx.x;

  if (tid < 64) {
    int Rg = blk * 64 + tid;
    int bond = Rg >> 3, batch = Rg & 7;
    int s = bonds[2 * bond], dn = bonds[2 * bond + 1];
    const float* xs = x + (size_t)(batch * NA + s) * 3;
    const float* xd = x + (size_t)(batch * NA + dn) * 3;
    float c0 = xd[0] - xs[0], c1 = xd[1] - xs[1], c2 = xd[2] - xs[2];
    cds[tid * 3 + 0] = c0; cds[tid * 3 + 1] = c1; cds[tid * 3 + 2] = c2;
    dists[tid] = sqrtf(c0 * c0 + c1 * c1 + c2 * c2);
  }
  if (tid < 128) {
    bm1s[tid] = bm1[tid]; bm2s[tid] = bm2[tid]; w1cs[tid] = w1c[tid];
    bc1s[tid] = bc1[tid]; wc2s[tid] = Wc2[tid];
  }
  __syncthreads();

  const int lane = tid & 63;
  const int quad = lane >> 4, l16 = lane & 15;
  const int wave = tid >> 6;
  const int rowBase = (wave >> 1) * 32;    // 2 row-groups of 32
  const int colG = wave & 1;               // 2 col-groups of 64
  const int colBase = colG * 64;
  const bf16x8* W1v = (const bf16x8*)W1p;
  const bf16x8* W2v = (const bf16x8*)W2p;
  const bf16x8* Wc1v = (const bf16x8*)Wc1p;

  // per-lane A-row metadata, two row sets (rowBase+l16, rowBase+16+l16)
  const int row0 = rowBase + l16, row1 = row0 + 16;
  const int Rg0 = blk * 64 + row0;
  const int bn0 = Rg0 >> 3, bat0 = Rg0 & 7;
  const bf16* hs0 = hb + (size_t)(bat0 * NA + bonds[2 * bn0]) * H;
  const bf16* hd0 = hb + (size_t)(bat0 * NA + bonds[2 * bn0 + 1]) * H;
  const int Rg1 = Rg0 + 16;
  const int bn1_ = Rg1 >> 3, bat1 = Rg1 & 7;
  const bf16* hs1 = hb + (size_t)(bat1 * NA + bonds[2 * bn1_]) * H;
  const bf16* hd1 = hb + (size_t)(bat1 * NA + bonds[2 * bn1_ + 1]) * H;
  const float dist0 = dists[row0], dist1 = dists[row1];

  f32x4 acc0[4], acc1[4];
#pragma unroll
  for (int nt = 0; nt < 4; nt++) {
    acc0[nt] = (f32x4){0.f, 0.f, 0.f, 0.f};
    acc1[nt] = (f32x4){0.f, 0.f, 0.f, 0.f};
  }

  // ---- layer 1: K = 256; swapped operands -> regs = 4 consecutive cols --
#pragma unroll
  for (int ks = 0; ks < 4; ks++) {
    bf16x8 a0 = *(const bf16x8*)(hs0 + ks * 32 + quad * 8);
    bf16x8 a1 = *(const bf16x8*)(hs1 + ks * 32 + quad * 8);
#pragma unroll
    for (int nt = 0; nt < 4; nt++) {
      bf16x8 b = W1v[((colG * 4 + nt) * 8 + ks) * 64 + lane];
      acc0[nt] = __builtin_amdgcn_mfma_f32_16x16x32_bf16(b, a0, acc0[nt], 0, 0, 0);
      acc1[nt] = __builtin_amdgcn_mfma_f32_16x16x32_bf16(b, a1, acc1[nt], 0, 0, 0);
    }
  }
#pragma unroll
  for (int ks = 4; ks < 8; ks++) {
    bf16x8 a0 = *(const bf16x8*)(hd0 + (ks - 4) * 32 + quad * 8);
    bf16x8 a1 = *(const bf16x8*)(hd1 + (ks - 4) * 32 + quad * 8);
#pragma unroll
    for (int nt = 0; nt < 4; nt++) {
      bf16x8 b = W1v[((colG * 4 + nt) * 8 + ks) * 64 + lane];
      acc0[nt] = __builtin_amdgcn_mfma_f32_16x16x32_bf16(b, a0, acc0[nt], 0, 0, 0);
      acc1[nt] = __builtin_amdgcn_mfma_f32_16x16x32_bf16(b, a1, acc1[nt], 0, 0, 0);
    }
  }
  // t1 epilogue -> Tbuf: one bf16x4 8B write per tile per row-set
#pragma unroll
  for (int nt = 0; nt < 4; nt++) {
    int col = colBase + nt * 16 + quad * 4;
    f32x4 bb = *(const f32x4*)&bm1s[col];
    f32x4 wc = *(const f32x4*)&w1cs[col];
    bf16x4 o0, o1;
#pragma unroll
    for (int reg = 0; reg < 4; reg++) {
      o0[reg] = (bf16)silu_f(acc0[nt][reg] + bb[reg] + dist0 * wc[reg]);
      o1[reg] = (bf16)silu_f(acc1[nt][reg] + bb[reg] + dist1 * wc[reg]);
    }
    *(bf16x4*)&Tbuf[tswz(row0, col)] = o0;
    *(bf16x4*)&Tbuf[tswz(row1, col)] = o1;
  }
  __syncthreads();   // T complete

  // ---- layer 2: K = 128 -> messages ----
#pragma unroll
  for (int nt = 0; nt < 4; nt++) {
    acc0[nt] = (f32x4){0.f, 0.f, 0.f, 0.f};
    acc1[nt] = (f32x4){0.f, 0.f, 0.f, 0.f};
  }
#pragma unroll
  for (int ks = 0; ks < 4; ks++) {
    bf16x8 a0 = *(const bf16x8*)&Tbuf[tswz(row0, ks * 32 + quad * 8)];
    bf16x8 a1 = *(const bf16x8*)&Tbuf[tswz(row1, ks * 32 + quad * 8)];
#pragma unroll
    for (int nt = 0; nt < 4; nt++) {
      bf16x8 b = W2v[((colG * 4 + nt) * 4 + ks) * 64 + lane];
      acc0[nt] = __builtin_amdgcn_mfma_f32_16x16x32_bf16(b, a0, acc0[nt], 0, 0, 0);
      acc1[nt] = __builtin_amdgcn_mfma_f32_16x16x32_bf16(b, a1, acc1[nt], 0, 0, 0);
    }
  }
  __syncthreads();   // all T reads done; safe to overwrite
#pragma unroll
  for (int nt = 0; nt < 4; nt++) {
    int col = colBase + nt * 16 + quad * 4;
    f32x4 bb = *(const f32x4*)&bm2s[col];
    bf16x4 o0, o1;
#pragma unroll
    for (int reg = 0; reg < 4; reg++) {
      o0[reg] = (bf16)silu_f(acc0[nt][reg] + bb[reg]);
      o1[reg] = (bf16)silu_f(acc1[nt][reg] + bb[reg]);
    }
    *(bf16x4*)&Tbuf[tswz(row0, col)] = o0;
    *(bf16x4*)&Tbuf[tswz(row1, col)] = o1;
  }
  __syncthreads();   // messages complete

  // ---- coord head ----
#pragma unroll
  for (int nt = 0; nt < 4; nt++) {
    acc0[nt] = (f32x4){0.f, 0.f, 0.f, 0.f};
    acc1[nt] = (f32x4){0.f, 0.f, 0.f, 0.f};
  }
#pragma unroll
  for (int ks = 0; ks < 4; ks++) {
    bf16x8 a0 = *(const bf16x8*)&Tbuf[tswz(row0, ks * 32 + quad * 8)];
    bf16x8 a1 = *(const bf16x8*)&Tbuf[tswz(row1, ks * 32 + quad * 8)];
#pragma unroll
    for (int nt = 0; nt < 4; nt++) {
      bf16x8 b = Wc1v[((colG * 4 + nt) * 4 + ks) * 64 + lane];
      acc0[nt] = __builtin_amdgcn_mfma_f32_16x16x32_bf16(b, a0, acc0[nt], 0, 0, 0);
      acc1[nt] = __builtin_amdgcn_mfma_f32_16x16x32_bf16(b, a1, acc1[nt], 0, 0, 0);
    }
  }

  // copy 64 message rows to global (4 x 16B chunks per thread, coalesced)
#pragma unroll
  for (int i = 0; i < 4; i++) {
    int item = i * 256 + tid;
    int row = item >> 4, cg = item & 15;
    *(bf16x8*)&msgOut[(size_t)(blk * 64 + row) * H + cg * 8] =
        *(const bf16x8*)&Tbuf[tswz(row, cg * 8)];
  }

  // lane-local sum over this lane's 16 cols, then reduce across quads
  float s0 = 0.f, s1 = 0.f;
#pragma unroll
  for (int nt = 0; nt < 4; nt++) {
    int col = colBase + nt * 16 + quad * 4;
    f32x4 bb = *(const f32x4*)&bc1s[col];
    f32x4 w2 = *(const f32x4*)&wc2s[col];
#pragma unroll
    for (int reg = 0; reg < 4; reg++) {
      s0 += silu_f(acc0[nt][reg] + bb[reg]) * w2[reg];
      s1 += silu_f(acc1[nt][reg] + bb[reg]) * w2[reg];
    }
  }
  s0 += __shfl_xor(s0, 16); s0 += __shfl_xor(s0, 32);
  s1 += __shfl_xor(s1, 16); s1 += __shfl_xor(s1, 32);
  if (quad == 0) {
    cwpart[colG][row0] = s0;
    cwpart[colG][row1] = s1;
  }
  __syncthreads();   // both col-halves' partials in
  if (colG == 0 && quad == 0) {
#pragma unroll
    for (int rs = 0; rs < 2; rs++) {
      int row = rs ? row1 : row0;
      size_t Rg = (size_t)blk * 64 + row;
      float cw = cwpart[0][row] + cwpart[1][row];
      float inv = 1.0f / (dists[row] + 1e-8f);
#pragma unroll
      for (int c = 0; c < 3; c++)
        updv[Rg * 3 + c] = cds[row * 3 + c] * inv * cw;
    }
  }
}

// ---------------- node kernel (64 rows; M=32 x N=64 phase-2) --------------
// Phase 1: thread = (row, 64B chunk): 4 threads/row, 2-way unrolled bond
// walk (8 x 16B msg loads in flight), fp32 acc -> bf16 Abuf. x_out fused.
// Phase 2: 4 waves, each 32 rows x 64 cols (2 acc sets share every W
// fragment, 1:2 B:MFMA — msg's r13 win ported).
__global__ __launch_bounds__(256, 4) void node_kernel(
    const float* __restrict__ h, const bf16* __restrict__ hb,
    const bf16* __restrict__ msg, const float* __restrict__ updv,
    const int* __restrict__ degI, const int* __restrict__ adj2,
    const bf16* __restrict__ Wn1p, const float* __restrict__ bn1,
    const bf16* __restrict__ Wn2p, const float* __restrict__ bn2,
    const float* __restrict__ x,
    float* __restrict__ hout, float* __restrict__ xout) {
  __shared__ __align__(16) bf16 Abuf[64 * 128];
  __shared__ __align__(16) bf16 Tbuf[64 * 128];

  const int tid = threadIdx.x, blk = blockIdx.x;

  // ---- phase 1: gather (64 rows x 4 chunks of 64B) ----
  {
    const int row = tid >> 2, c4 = tid & 3;
    const int Rg = blk * 64 + row;                // batch*NA + atom
    const int atomA = Rg % NA, batA = Rg / NA;
    int deg = degI[atomA];
    if (deg > ADJ_CAP) deg = ADJ_CAP;
    const int* ap = adj2 + atomA * ADJ_CAP;
    float a32[32];
#pragma unroll
    for (int t = 0; t < 32; t++) a32[t] = 0.f;
    float sx = 0.f, sy = 0.f, sz = 0.f;
    int j = 0;
    for (; j + 2 <= deg; j += 2) {
      int2 e2 = *(const int2*)&ap[j];
      const bf16* m0 = msg + ((size_t)(e2.x >> 1) * 8 + batA) * H + c4 * 32;
      const bf16* m1 = msg + ((size_t)(e2.y >> 1) * 8 + batA) * H + c4 * 32;
      bf16x8 v0 = *(const bf16x8*)(m0),      v1 = *(const bf16x8*)(m0 + 8);
      bf16x8 v2 = *(const bf16x8*)(m0 + 16), v3 = *(const bf16x8*)(m0 + 24);
      bf16x8 u0 = *(const bf16x8*)(m1),      u1 = *(const bf16x8*)(m1 + 8);
      bf16x8 u2 = *(const bf16x8*)(m1 + 16), u3 = *(const bf16x8*)(m1 + 24);
      if (c4 == 0) {
        float sg0 = (e2.x & 1) ? 1.0f : -1.0f;
        float sg1 = (e2.y & 1) ? 1.0f : -1.0f;
        const float* uv0 = updv + ((size_t)(e2.x >> 1) * 8 + batA) * 3;
        const float* uv1 = updv + ((size_t)(e2.y >> 1) * 8 + batA) * 3;
        sx += sg0 * uv0[0] + sg1 * uv1[0];
        sy += sg0 * uv0[1] + sg1 * uv1[1];
        sz += sg0 * uv0[2] + sg1 * uv1[2];
      }
#pragma unroll
      for (int t = 0; t < 8; t++) {
        a32[t]      += (float)v0[t] + (float)u0[t];
        a32[8 + t]  += (float)v1[t] + (float)u1[t];
        a32[16 + t] += (float)v2[t] + (float)u2[t];
        a32[24 + t] += (float)v3[t] + (float)u3[t];
      }
    }
    if (j < deg) {
      int ent0 = ap[j];
      const bf16* m0 = msg + ((size_t)(ent0 >> 1) * 8 + batA) * H + c4 * 32;
      if (c4 == 0) {
        float sg0 = (ent0 & 1) ? 1.0f : -1.0f;
        const float* uv0 = updv + ((size_t)(ent0 >> 1) * 8 + batA) * 3;
        sx += sg0 * uv0[0]; sy += sg0 * uv0[1]; sz += sg0 * uv0[2];
      }
#pragma unroll
      for (int k = 0; k < 4; k++) {
        bf16x8 v = *(const bf16x8*)(m0 + 8 * k);
#pragma unroll
        for (int t = 0; t < 8; t++) a32[8 * k + t] += (float)v[t];
      }
    }
    if (c4 == 0) {   // x finalize
      float cnt = deg < 1 ? 1.0f : (float)deg;
      float inv = 1.0f / cnt;
      size_t o = (size_t)Rg * 3;
      xout[o + 0] = x[o + 0] + sx * inv;
      xout[o + 1] = x[o + 1] + sy * inv;
      xout[o + 2] = x[o + 2] + sz * inv;
    }
#pragma unroll
    for (int k = 0; k < 4; k++) {
      bf16x8 w;
#pragma unroll
      for (int t = 0; t < 8; t++) w[t] = (bf16)a32[8 * k + t];
      *(bf16x8*)&Abuf[tswz(row, c4 * 32 + 8 * k)] = w;
    }
  }
  __syncthreads();   // agg tile ready

  // ---- phase 2: node MLP, M=32 x N=64 per wave, swapped MFMA ----
  const int lane = tid & 63, wave = tid >> 6;
  const int quad = lane >> 4, l16 = lane & 15;
  const int rowBase = (wave >> 1) * 32, colG = wave & 1, colBase = colG * 64;
  const int row0 = rowBase + l16, row1 = row0 + 16;
  const size_t RgA0 = (size_t)blk * 64 + row0;
  const size_t RgA1 = RgA0 + 16;
  const bf16* hrow0 = hb + RgA0 * H;
  const bf16* hrow1 = hb + RgA1 * H;
  const bf16x8* W1v = (const bf16x8*)Wn1p;
  const bf16x8* W2v = (const bf16x8*)Wn2p;

  f32x4 acc0[4], acc1[4];
#pragma unroll
  for (int nt = 0; nt < 4; nt++) {
    acc0[nt] = (f32x4){0.f, 0.f, 0.f, 0.f};
    acc1[nt] = (f32x4){0.f, 0.f, 0.f, 0.f};
  }

  // layer-1 first half: h (bf16) register-direct from global
#pragma unroll
  for (int ks = 0; ks < 4; ks++) {
    bf16x8 a0 = *(const bf16x8*)(hrow0 + ks * 32 + quad * 8);
    bf16x8 a1 = *(const bf16x8*)(hrow1 + ks * 32 + quad * 8);
#pragma unroll
    for (int nt = 0; nt < 4; nt++) {
      bf16x8 b = W1v[((colG * 4 + nt) * 8 + ks) * 64 + lane];
      acc0[nt] = __builtin_amdgcn_mfma_f32_16x16x32_bf16(b, a0, acc0[nt], 0, 0, 0);
      acc1[nt] = __builtin_amdgcn_mfma_f32_16x16x32_bf16(b, a1, acc1[nt], 0, 0, 0);
    }
  }
  // layer-1 second half: aggregated from LDS
#pragma unroll
  for (int ks2 = 0; ks2 < 4; ks2++) {
    bf16x8 a0 = *(const bf16x8*)&Abuf[tswz(row0, ks2 * 32 + quad * 8)];
    bf16x8 a1 = *(const bf16x8*)&Abuf[tswz(row1, ks2 * 32 + quad * 8)];
#pragma unroll
    for (int nt = 0; nt < 4; nt++) {
      bf16x8 b = W1v[((colG * 4 + nt) * 8 + 4 + ks2) * 64 + lane];
      acc0[nt] = __builtin_amdgcn_mfma_f32_16x16x32_bf16(b, a0, acc0[nt], 0, 0, 0);
      acc1[nt] = __builtin_amdgcn_mfma_f32_16x16x32_bf16(b, a1, acc1[nt], 0, 0, 0);
    }
  }
#pragma unroll
  for (int nt = 0; nt < 4; nt++) {
    int col = colBase + nt * 16 + quad * 4;
    f32x4 bb = *(const f32x4*)&bn1[col];
    bf16x4 o0, o1;
#pragma unroll
    for (int reg = 0; reg < 4; reg++) {
      o0[reg] = (bf16)silu_f(acc0[nt][reg] + bb[reg]);
      o1[reg] = (bf16)silu_f(acc1[nt][reg] + bb[reg]);
    }
    *(bf16x4*)&Tbuf[tswz(row0, col)] = o0;
    *(bf16x4*)&Tbuf[tswz(row1, col)] = o1;
  }
  __syncthreads();   // T complete (both col halves)

#pragma unroll
  for (int nt = 0; nt < 4; nt++) {
    acc0[nt] = (f32x4){0.f, 0.f, 0.f, 0.f};
    acc1[nt] = (f32x4){0.f, 0.f, 0.f, 0.f};
  }
#pragma unroll
  for (int ks = 0; ks < 4; ks++) {
    bf16x8 a0 = *(const bf16x8*)&Tbuf[tswz(row0, ks * 32 + quad * 8)];
    bf16x8 a1 = *(const bf16x8*)&Tbuf[tswz(row1, ks * 32 + quad * 8)];
#pragma unroll
    for (int nt = 0; nt < 4; nt++) {
      bf16x8 b = W2v[((colG * 4 + nt) * 4 + ks) * 64 + lane];
      acc0[nt] = __builtin_amdgcn_mfma_f32_16x16x32_bf16(b, a0, acc0[nt], 0, 0, 0);
      acc1[nt] = __builtin_amdgcn_mfma_f32_16x16x32_bf16(b, a1, acc1[nt], 0, 0, 0);
    }
  }
#pragma unroll
  for (int nt = 0; nt < 4; nt++) {
    int col = colBase + nt * 16 + quad * 4;
    f32x4 bb = *(const f32x4*)&bn2[col];
    f32x4 hv0 = *(const f32x4*)&h[RgA0 * H + col];
    f32x4 hv1 = *(const f32x4*)&h[RgA1 * H + col];
    f32x4 o0, o1;
#pragma unroll
    for (int reg = 0; reg < 4; reg++) {
      o0[reg] = hv0[reg] + acc0[nt][reg] + bb[reg];
      o1[reg] = hv1[reg] + acc1[nt][reg] + bb[reg];
    }
    *(f32x4*)&hout[RgA0 * H + col] = o0;
    *(f32x4*)&hout[RgA1 * H + col] = o1;
  }
}

extern "C" void kernel_launch(void* const* d_in, const int* in_sizes, int n_in,
                              void* d_out, int out_size, void* d_ws,
                              size_t ws_size, hipStream_t stream) {
  const float* h    = (const float*)d_in[0];
  const float* x    = (const float*)d_in[1];
  const int*  bonds = (const int*)d_in[2];
  const float* Wm1  = (const float*)d_in[3];
  const float* bm1  = (const float*)d_in[4];
  const float* Wm2  = (const float*)d_in[5];
  const float* bm2  = (const float*)d_in[6];
  const float* Wn1  = (const float*)d_in[7];
  const float* bn1  = (const float*)d_in[8];
  const float* Wn2  = (const float*)d_in[9];
  const float* bn2  = (const float*)d_in[10];
  const float* Wc1  = (const float*)d_in[11];
  const float* bc1  = (const float*)d_in[12];
  const float* Wc2  = (const float*)d_in[13];

  float* out  = (float*)d_out;
  float* hout = out;
  float* xout = out + (size_t)NBATCH * NA * H;

  char* ws = (char*)d_ws;
  // layout (bytes): NEED = 172,553,216 < 173,080,576 proven available.
  const size_t OFF_DEG  = 0;                        // NA int = 80,000
  const size_t OFF_W1   = 163840;                   // 65,536
  const size_t OFF_W2   = OFF_W1 + 65536;           // 32,768
  const size_t OFF_WN1  = OFF_W2 + 32768;           // 65,536
  const size_t OFF_WN2  = OFF_WN1 + 65536;          // 32,768
  const size_t OFF_WC1  = OFF_WN2 + 32768;          // 32,768 (ends 393,216)
  const size_t OFF_ADJ2 = 393216;                   // NA*32 int = 2,560,000
  const size_t OFF_UPDV = 2953216;                  // NB*8*3 f32 = 5,760,000
  const size_t OFF_HB   = 8713216;                  // 160000*128 bf16 = 40,960,000
  const size_t OFF_MSG  = 49673216;                 // NB*8*128 bf16 = 122,880,000

  int*   degI = (int*)(ws + OFF_DEG);
  bf16*  W1p  = (bf16*)(ws + OFF_W1);
  bf16*  W2p  = (bf16*)(ws + OFF_W2);
  bf16*  Wn1p = (bf16*)(ws + OFF_WN1);
  bf16*  Wn2p = (bf16*)(ws + OFF_WN2);
  bf16*  Wc1p = (bf16*)(ws + OFF_WC1);
  int*   adj2 = (int*)(ws + OFF_ADJ2);
  float* updv = (float*)(ws + OFF_UPDV);
  bf16*  hb   = (bf16*)(ws + OFF_HB);
  bf16*  msgB = (bf16*)(ws + OFF_MSG);

  (void)hipMemsetAsync(degI, 0, NA * sizeof(int), stream);

  cast_h<<<NBATCH * NA * H / 1024, 256, 0, stream>>>(h, hb);
  pack_all<<<448, 256, 0, stream>>>(Wm1, Wm2, Wn1, Wn2, Wc1,
                                    W1p, W2p, Wn1p, Wn2p, Wc1p);
  build_adj2<<<(NB + 255) / 256, 256, 0, stream>>>(bonds, degI, adj2);

  msg_kernel<<<NB * NBATCH / 64, 256, 0, stream>>>(
      hb, x, bonds, W1p, bm1, W2p, bm2, Wm1 + 256 * H, Wc1p, bc1, Wc2,
      msgB, updv);
  node_kernel<<<NBATCH * NA / 64, 256, 0, stream>>>(
      h, hb, msgB, updv, degI, adj2, Wn1p, bn1, Wn2p, bn2, x,
      hout, xout);
}

// Round 13
// 432.228 us; speedup vs baseline: 1.0640x; 1.0018x over previous
//
#include <hip/hip_runtime.h>

// BondAwareEGNN fused layer — round 18.
//
// Round-17 post-mortem: matched (460->433). msg = r15 exact (162us, no
// spill); node M=32xN=64 port gave ~-27us. B-reuse has been the most
// reliable lever (r13: 1:1->1:2 = -50us on msg).
//
// Round-18:
//   1. msg M=48xN=64 (3 row-sets/wave): acc 48 AGPR + ~60 VGPR ~= 108
//      < 128 cap (r8's failed variant was 64 AGPR + 8-nt addressing).
//      Block = 96 rows (grid 5000), LDS ~29KB. B:MFMA 1:3. Spill guard:
//      WRITE ~125.6MB, VGPR_Count >= 48; violation -> revert M=32.
//   2. cast_h + pack_all + build_adj2 fused into one prep_kernel
//      (block-range dispatch): 6 -> 4 dispatches.
//   3. node unchanged (just won; don't stack risk).

#define H      128
#define NA     20000
#define NB     60000
#define NBATCH 8
#define ADJ_CAP 32

typedef __bf16 bf16;
typedef __bf16 bf16x4 __attribute__((ext_vector_type(4)));
typedef __bf16 bf16x8 __attribute__((ext_vector_type(8)));
typedef float  f32x4  __attribute__((ext_vector_type(4)));

__device__ __forceinline__ float silu_f(float v) {
  float e = __expf(-v);
  return v * __builtin_amdgcn_rcpf(1.0f + e);  // 1-ulp rcp; inf -> 0 ok
}

// XOR-swizzled index into a [R][128] bf16 tile. Row stride 256B (bank
// neutral); 16B chunk index XOR'd with row&7 rotates banks. Bijective per
// row; 8-element chunks stay contiguous so bf16x8/bf16x4 ops still work.
__device__ __forceinline__ int tswz(int row, int col) {
  return (row << 7) + (((((col) >> 3) ^ (row & 7)) << 3) | (col & 7));
}

// fp32 KxN(128) row-major -> bf16 fragment-linear (8 bf16 per lane-frag).
__device__ __forceinline__ void pack_one(const float* __restrict__ src,
                                         bf16* __restrict__ dst, int K,
                                         int i) {
  int k = i >> 7, n = i & 127;
  int nt = n >> 4, ks = k >> 5;
  int lane = (((k >> 3) & 3) << 4) | (n & 15);
  int j = k & 7;
  int KS = K >> 5;
  dst[((((nt * KS + ks) * 64) + lane) << 3) + j] = (bf16)src[i];
}

// cast_h (20000 blks) + pack_all (448 blks) + build_adj2 (235 blks) fused.
#define PREP_CAST_BLKS 20000
#define PREP_PACK_BLKS 448
#define PREP_ADJ_BLKS  235
__global__ void prep_kernel(const float* __restrict__ h, bf16* __restrict__ hb,
                            const float* __restrict__ Wm1,
                            const float* __restrict__ Wm2,
                            const float* __restrict__ Wn1,
                            const float* __restrict__ Wn2,
                            const float* __restrict__ Wc1,
                            bf16* __restrict__ W1p, bf16* __restrict__ W2p,
                            bf16* __restrict__ Wn1p, bf16* __restrict__ Wn2p,
                            bf16* __restrict__ Wc1p,
                            const int* __restrict__ bonds,
                            int* __restrict__ degI, int* __restrict__ adj2) {
  const int blk = blockIdx.x;
  if (blk < PREP_CAST_BLKS) {
    int i = blk * 256 + threadIdx.x;  // one float4 per thread
    float4 v = *(const float4*)(h + (size_t)i * 4);
    bf16x4 t = {(bf16)v.x, (bf16)v.y, (bf16)v.z, (bf16)v.w};
    *(bf16x4*)(hb + (size_t)i * 4) = t;
  } else if (blk < PREP_CAST_BLKS + PREP_PACK_BLKS) {
    int i = (blk - PREP_CAST_BLKS) * 256 + threadIdx.x;
    if (i < 32768)       pack_one(Wm1, W1p, 256, i);
    else if (i < 49152)  pack_one(Wm2, W2p, 128, i - 32768);
    else if (i < 81920)  pack_one(Wn1, Wn1p, 256, i - 49152);
    else if (i < 98304)  pack_one(Wn2, Wn2p, 128, i - 81920);
    else if (i < 114688) pack_one(Wc1, Wc1p, 128, i - 98304);
  } else {
    int e = (blk - PREP_CAST_BLKS - PREP_PACK_BLKS) * 256 + threadIdx.x;
    if (e < NB) {
      int s = bonds[2 * e], d = bonds[2 * e + 1];
      int p = atomicAdd(&degI[s], 1);
      if (p < ADJ_CAP) adj2[s * ADJ_CAP + p] = (e << 1);      // src: sign -
      p = atomicAdd(&degI[d], 1);
      if (p < ADJ_CAP) adj2[d * ADJ_CAP + p] = (e << 1) | 1;  // dst: sign +
    }
  }
}

// ---------------- message kernel (M=48 x N=64 per wave, swapped MFMA) ----
__global__ __launch_bounds__(256, 4) void msg_kernel(
    const bf16* __restrict__ hb, const float* __restrict__ x,
    const int* __restrict__ bonds,
    const bf16* __restrict__ W1p, const float* __restrict__ bm1,
    const bf16* __restrict__ W2p, const float* __restrict__ bm2,
    const float* __restrict__ w1c,   // Wm1 row 256 (dist row), fp32[128]
    const bf16* __restrict__ Wc1p, const float* __restrict__ bc1,
    const float* __restrict__ Wc2,
    bf16* __restrict__ msgOut, float* __restrict__ updv) {
  // [96][128] swizzled tile: T after layer-1, messages after layer-2.
  __shared__ __align__(16) bf16 Tbuf[96 * 128];
  __shared__ __align__(16) float cds[96 * 3];
  __shared__ __align__(16) float dists[96];
  __shared__ __align__(16) float bm1s[128], bm2s[128], w1cs[128];
  __shared__ __align__(16) float bc1s[128], wc2s[128];
  __shared__ float cwpart[2][96];

  const int tid = threadIdx.x, blk = blockIdx.x;

  if (tid < 96) {
    int Rg = blk * 96 + tid;
    int bond = Rg >> 3, batch = Rg & 7;
    int s = bonds[2 * bond], dn = bonds[2 * bond + 1];
    const float* xs = x + (size_t)(batch * NA + s) * 3;
    const float* xd = x + (size_t)(batch * NA + dn) * 3;
    float c0 = xd[0] - xs[0], c1 = xd[1] - xs[1], c2 = xd[2] - xs[2];
    cds[tid * 3 + 0] = c0; cds[tid * 3 + 1] = c1; cds[tid * 3 + 2] = c2;
    dists[tid] = sqrtf(c0 * c0 + c1 * c1 + c2 * c2);
  }
  if (tid < 128) {
    bm1s[tid] = bm1[tid]; bm2s[tid] = bm2[tid]; w1cs[tid] = w1c[tid];
    bc1s[tid] = bc1[tid]; wc2s[tid] = Wc2[tid];
  }
  __syncthreads();

  const int lane = tid & 63;
  const int quad = lane >> 4, l16 = lane & 15;
  const int wave = tid >> 6;
  const int rowBase = (wave >> 1) * 48;    // 2 row-groups of 48
  const int colG = wave & 1;               // 2 col-groups of 64
  const int colBase = colG * 64;
  const bf16x8* W1v = (const bf16x8*)W1p;
  const bf16x8* W2v = (const bf16x8*)W2p;
  const bf16x8* Wc1v = (const bf16x8*)Wc1p;

  // per-lane A-row metadata, three row sets
  const int row0 = rowBase + l16, row1 = row0 + 16, row2 = row0 + 32;
  const int Rg0 = blk * 96 + row0;
  const int bn0 = Rg0 >> 3, bat0 = Rg0 & 7;
  const bf16* hs0 = hb + (size_t)(bat0 * NA + bonds[2 * bn0]) * H;
  const bf16* hd0 = hb + (size_t)(bat0 * NA + bonds[2 * bn0 + 1]) * H;
  const int Rg1 = Rg0 + 16;
  const int bn1_ = Rg1 >> 3, bat1 = Rg1 & 7;
  const bf16* hs1 = hb + (size_t)(bat1 * NA + bonds[2 * bn1_]) * H;
  const bf16* hd1 = hb + (size_t)(bat1 * NA + bonds[2 * bn1_ + 1]) * H;
  const int Rg2 = Rg0 + 32;
  const int bn2_ = Rg2 >> 3, bat2 = Rg2 & 7;
  const bf16* hs2 = hb + (size_t)(bat2 * NA + bonds[2 * bn2_]) * H;
  const bf16* hd2 = hb + (size_t)(bat2 * NA + bonds[2 * bn2_ + 1]) * H;
  const float dist0 = dists[row0], dist1 = dists[row1], dist2 = dists[row2];

  f32x4 acc0[4], acc1[4], acc2[4];
#pragma unroll
  for (int nt = 0; nt < 4; nt++) {
    acc0[nt] = (f32x4){0.f, 0.f, 0.f, 0.f};
    acc1[nt] = (f32x4){0.f, 0.f, 0.f, 0.f};
    acc2[nt] = (f32x4){0.f, 0.f, 0.f, 0.f};
  }

  // ---- layer 1: K = 256; each B fragment feeds 3 MFMAs ----
#pragma unroll
  for (int ks = 0; ks < 4; ks++) {
    bf16x8 a0 = *(const bf16x8*)(hs0 + ks * 32 + quad * 8);
    bf16x8 a1 = *(const bf16x8*)(hs1 + ks * 32 + quad * 8);
    bf16x8 a2 = *(const bf16x8*)(hs2 + ks * 32 + quad * 8);
#pragma unroll
    for (int nt = 0; nt < 4; nt++) {
      bf16x8 b = W1v[((colG * 4 + nt) * 8 + ks) * 64 + lane];
      acc0[nt] = __builtin_amdgcn_mfma_f32_16x16x32_bf16(b, a0, acc0[nt], 0, 0, 0);
      acc1[nt] = __builtin_amdgcn_mfma_f32_16x16x32_bf16(b, a1, acc1[nt], 0, 0, 0);
      acc2[nt] = __builtin_amdgcn_mfma_f32_16x16x32_bf16(b, a2, acc2[nt], 0, 0, 0);
    }
  }
#pragma unroll
  for (int ks = 4; ks < 8; ks++) {
    bf16x8 a0 = *(const bf16x8*)(hd0 + (ks - 4) * 32 + quad * 8);
    bf16x8 a1 = *(const bf16x8*)(hd1 + (ks - 4) * 32 + quad * 8);
    bf16x8 a2 = *(const bf16x8*)(hd2 + (ks - 4) * 32 + quad * 8);
#pragma unroll
    for (int nt = 0; nt < 4; nt++) {
      bf16x8 b = W1v[((colG * 4 + nt) * 8 + ks) * 64 + lane];
      acc0[nt] = __builtin_amdgcn_mfma_f32_16x16x32_bf16(b, a0, acc0[nt], 0, 0, 0);
      acc1[nt] = __builtin_amdgcn_mfma_f32_16x16x32_bf16(b, a1, acc1[nt], 0, 0, 0);
      acc2[nt] = __builtin_amdgcn_mfma_f32_16x16x32_bf16(b, a2, acc2[nt], 0, 0, 0);
    }
  }
  // t1 epilogue -> Tbuf: one bf16x4 8B write per tile per row-set
#pragma unroll
  for (int nt = 0; nt < 4; nt++) {
    int col = colBase + nt * 16 + quad * 4;
    f32x4 bb = *(const f32x4*)&bm1s[col];
    f32x4 wc = *(const f32x4*)&w1cs[col];
    bf16x4 o0, o1, o2;
#pragma unroll
    for (int reg = 0; reg < 4; reg++) {
      o0[reg] = (bf16)silu_f(acc0[nt][reg] + bb[reg] + dist0 * wc[reg]);
      o1[reg] = (bf16)silu_f(acc1[nt][reg] + bb[reg] + dist1 * wc[reg]);
      o2[reg] = (bf16)silu_f(acc2[nt][reg] + bb[reg] + dist2 * wc[reg]);
    }
    *(bf16x4*)&Tbuf[tswz(row0, col)] = o0;
    *(bf16x4*)&Tbuf[tswz(row1, col)] = o1;
    *(bf16x4*)&Tbuf[tswz(row2, col)] = o2;
  }
  __syncthreads();   // T complete

  // ---- layer 2: K = 128 -> messages ----
#pragma unroll
  for (int nt = 0; nt < 4; nt++) {
    acc0[nt] = (f32x4){0.f, 0.f, 0.f, 0.f};
    acc1[nt] = (f32x4){0.f, 0.f, 0.f, 0.f};
    acc2[nt] = (f32x4){0.f, 0.f, 0.f, 0.f};
  }
#pragma unroll
  for (int ks = 0; ks < 4; ks++) {
    bf16x8 a0 = *(const bf16x8*)&Tbuf[tswz(row0, ks * 32 + quad * 8)];
    bf16x8 a1 = *(const bf16x8*)&Tbuf[tswz(row1, ks * 32 + quad * 8)];
    bf16x8 a2 = *(const bf16x8*)&Tbuf[tswz(row2, ks * 32 + quad * 8)];
#pragma unroll
    for (int nt = 0; nt < 4; nt++) {
      bf16x8 b = W2v[((colG * 4 + nt) * 4 + ks) * 64 + lane];
      acc0[nt] = __builtin_amdgcn_mfma_f32_16x16x32_bf16(b, a0, acc0[nt], 0, 0, 0);
      acc1[nt] = __builtin_amdgcn_mfma_f32_16x16x32_bf16(b, a1, acc1[nt], 0, 0, 0);
      acc2[nt] = __builtin_amdgcn_mfma_f32_16x16x32_bf16(b, a2, acc2[nt], 0, 0, 0);
    }
  }
  __syncthreads();   // all T reads done; safe to overwrite
#pragma unroll
  for (int nt = 0; nt < 4; nt++) {
    int col = colBase + nt * 16 + quad * 4;
    f32x4 bb = *(const f32x4*)&bm2s[col];
    bf16x4 o0, o1, o2;
#pragma unroll
    for (int reg = 0; reg < 4; reg++) {
      o0[reg] = (bf16)silu_f(acc0[nt][reg] + bb[reg]);
      o1[reg] = (bf16)silu_f(acc1[nt][reg] + bb[reg]);
      o2[reg] = (bf16)silu_f(acc2[nt][reg] + bb[reg]);
    }
    *(bf16x4*)&Tbuf[tswz(row0, col)] = o0;
    *(bf16x4*)&Tbuf[tswz(row1, col)] = o1;
    *(bf16x4*)&Tbuf[tswz(row2, col)] = o2;
  }
  __syncthreads();   // messages complete

  // ---- coord head ----
#pragma unroll
  for (int nt = 0; nt < 4; nt++) {
    acc0[nt] = (f32x4){0.f, 0.f, 0.f, 0.f};
    acc1[nt] = (f32x4){0.f, 0.f, 0.f, 0.f};
    acc2[nt] = (f32x4){0.f, 0.f, 0.f, 0.f};
  }
#pragma unroll
  for (int ks = 0; ks < 4; ks++) {
    bf16x8 a0 = *(const bf16x8*)&Tbuf[tswz(row0, ks * 32 + quad * 8)];
    bf16x8 a1 = *(const bf16x8*)&Tbuf[tswz(row1, ks * 32 + quad * 8)];
    bf16x8 a2 = *(const bf16x8*)&Tbuf[tswz(row2, ks * 32 + quad * 8)];
#pragma unroll
    for (int nt = 0; nt < 4; nt++) {
      bf16x8 b = Wc1v[((colG * 4 + nt) * 4 + ks) * 64 + lane];
      acc0[nt] = __builtin_amdgcn_mfma_f32_16x16x32_bf16(b, a0, acc0[nt], 0, 0, 0);
      acc1[nt] = __builtin_amdgcn_mfma_f32_16x16x32_bf16(b, a1, acc1[nt], 0, 0, 0);
      acc2[nt] = __builtin_amdgcn_mfma_f32_16x16x32_bf16(b, a2, acc2[nt], 0, 0, 0);
    }
  }

  // copy 96 message rows to global (6 x 16B chunks per thread, coalesced)
#pragma unroll
  for (int i = 0; i < 6; i++) {
    int item = i * 256 + tid;
    int row = item >> 4, cg = item & 15;
    *(bf16x8*)&msgOut[(size_t)(blk * 96 + row) * H + cg * 8] =
        *(const bf16x8*)&Tbuf[tswz(row, cg * 8)];
  }

  // lane-local sum over this lane's 16 cols, then reduce across quads
  float s0 = 0.f, s1 = 0.f, s2 = 0.f;
#pragma unroll
  for (int nt = 0; nt < 4; nt++) {
    int col = colBase + nt * 16 + quad * 4;
    f32x4 bb = *(const f32x4*)&bc1s[col];
    f32x4 w2 = *(const f32x4*)&wc2s[col];
#pragma unroll
    for (int reg = 0; reg < 4; reg++) {
      s0 += silu_f(acc0[nt][reg] + bb[reg]) * w2[reg];
      s1 += silu_f(acc1[nt][reg] + bb[reg]) * w2[reg];
      s2 += silu_f(acc2[nt][reg] + bb[reg]) * w2[reg];
    }
  }
  s0 += __shfl_xor(s0, 16); s0 += __shfl_xor(s0, 32);
  s1 += __shfl_xor(s1, 16); s1 += __shfl_xor(s1, 32);
  s2 += __shfl_xor(s2, 16); s2 += __shfl_xor(s2, 32);
  if (quad == 0) {
    cwpart[colG][row0] = s0;
    cwpart[colG][row1] = s1;
    cwpart[colG][row2] = s2;
  }
  __syncthreads();   // both col-halves' partials in
  if (colG == 0 && quad == 0) {
#pragma unroll
    for (int rs = 0; rs < 3; rs++) {
      int row = row0 + rs * 16;
      size_t Rg = (size_t)blk * 96 + row;
      float cw = cwpart[0][row] + cwpart[1][row];
      float inv = 1.0f / (dists[row] + 1e-8f);
#pragma unroll
      for (int c = 0; c < 3; c++)
        updv[Rg * 3 + c] = cds[row * 3 + c] * inv * cw;
    }
  }
}

// ---------------- node kernel (64 rows; M=32 x N=64 phase-2) --------------
// Phase 1: thread = (row, 64B chunk): 4 threads/row, 2-way unrolled bond
// walk (8 x 16B msg loads in flight), fp32 acc -> bf16 Abuf. x_out fused.
// Phase 2: 4 waves, each 32 rows x 64 cols (2 acc sets share every W
// fragment, 1:2 B:MFMA).
__global__ __launch_bounds__(256, 4) void node_kernel(
    const float* __restrict__ h, const bf16* __restrict__ hb,
    const bf16* __restrict__ msg, const float* __restrict__ updv,
    const int* __restrict__ degI, const int* __restrict__ adj2,
    const bf16* __restrict__ Wn1p, const float* __restrict__ bn1,
    const bf16* __restrict__ Wn2p, const float* __restrict__ bn2,
    const float* __restrict__ x,
    float* __restrict__ hout, float* __restrict__ xout) {
  __shared__ __align__(16) bf16 Abuf[64 * 128];
  __shared__ __align__(16) bf16 Tbuf[64 * 128];

  const int tid = threadIdx.x, blk = blockIdx.x;

  // ---- phase 1: gather (64 rows x 4 chunks of 64B) ----
  {
    const int row = tid >> 2, c4 = tid & 3;
    const int Rg = blk * 64 + row;                // batch*NA + atom
    const int atomA = Rg % NA, batA = Rg / NA;
    int deg = degI[atomA];
    if (deg > ADJ_CAP) deg = ADJ_CAP;
    const int* ap = adj2 + atomA * ADJ_CAP;
    float a32[32];
#pragma unroll
    for (int t = 0; t < 32; t++) a32[t] = 0.f;
    float sx = 0.f, sy = 0.f, sz = 0.f;
    int j = 0;
    for (; j + 2 <= deg; j += 2) {
      int2 e2 = *(const int2*)&ap[j];
      const bf16* m0 = msg + ((size_t)(e2.x >> 1) * 8 + batA) * H + c4 * 32;
      const bf16* m1 = msg + ((size_t)(e2.y >> 1) * 8 + batA) * H + c4 * 32;
      bf16x8 v0 = *(const bf16x8*)(m0),      v1 = *(const bf16x8*)(m0 + 8);
      bf16x8 v2 = *(const bf16x8*)(m0 + 16), v3 = *(const bf16x8*)(m0 + 24);
      bf16x8 u0 = *(const bf16x8*)(m1),      u1 = *(const bf16x8*)(m1 + 8);
      bf16x8 u2 = *(const bf16x8*)(m1 + 16), u3 = *(const bf16x8*)(m1 + 24);
      if (c4 == 0) {
        float sg0 = (e2.x & 1) ? 1.0f : -1.0f;
        float sg1 = (e2.y & 1) ? 1.0f : -1.0f;
        const float* uv0 = updv + ((size_t)(e2.x >> 1) * 8 + batA) * 3;
        const float* uv1 = updv + ((size_t)(e2.y >> 1) * 8 + batA) * 3;
        sx += sg0 * uv0[0] + sg1 * uv1[0];
        sy += sg0 * uv0[1] + sg1 * uv1[1];
        sz += sg0 * uv0[2] + sg1 * uv1[2];
      }
#pragma unroll
      for (int t = 0; t < 8; t++) {
        a32[t]      += (float)v0[t] + (float)u0[t];
        a32[8 + t]  += (float)v1[t] + (float)u1[t];
        a32[16 + t] += (float)v2[t] + (float)u2[t];
        a32[24 + t] += (float)v3[t] + (float)u3[t];
      }
    }
    if (j < deg) {
      int ent0 = ap[j];
      const bf16* m0 = msg + ((size_t)(ent0 >> 1) * 8 + batA) * H + c4 * 32;
      if (c4 == 0) {
        float sg0 = (ent0 & 1) ? 1.0f : -1.0f;
        const float* uv0 = updv + ((size_t)(ent0 >> 1) * 8 + batA) * 3;
        sx += sg0 * uv0[0]; sy += sg0 * uv0[1]; sz += sg0 * uv0[2];
      }
#pragma unroll
      for (int k = 0; k < 4; k++) {
        bf16x8 v = *(const bf16x8*)(m0 + 8 * k);
#pragma unroll
        for (int t = 0; t < 8; t++) a32[8 * k + t] += (float)v[t];
      }
    }
    if (c4 == 0) {   // x finalize
      float cnt = deg < 1 ? 1.0f : (float)deg;
      float inv = 1.0f / cnt;
      size_t o = (size_t)Rg * 3;
      xout[o + 0] = x[o + 0] + sx * inv;
      xout[o + 1] = x[o + 1] + sy * inv;
      xout[o + 2] = x[o + 2] + sz * inv;
    }
#pragma unroll
    for (int k = 0; k < 4; k++) {
      bf16x8 w;
#pragma unroll
      for (int t = 0; t < 8; t++) w[t] = (bf16)a32[8 * k + t];
      *(bf16x8*)&Abuf[tswz(row, c4 * 32 + 8 * k)] = w;
    }
  }
  __syncthreads();   // agg tile ready

  // ---- phase 2: node MLP, M=32 x N=64 per wave, swapped MFMA ----
  const int lane = tid & 63, wave = tid >> 6;
  const int quad = lane >> 4, l16 = lane & 15;
  const int rowBase = (wave >> 1) * 32, colG = wave & 1, colBase = colG * 64;
  const int row0 = rowBase + l16, row1 = row0 + 16;
  const size_t RgA0 = (size_t)blk * 64 + row0;
  const size_t RgA1 = RgA0 + 16;
  const bf16* hrow0 = hb + RgA0 * H;
  const bf16* hrow1 = hb + RgA1 * H;
  const bf16x8* W1v = (const bf16x8*)Wn1p;
  const bf16x8* W2v = (const bf16x8*)Wn2p;

  f32x4 acc0[4], acc1[4];
#pragma unroll
  for (int nt = 0; nt < 4; nt++) {
    acc0[nt] = (f32x4){0.f, 0.f, 0.f, 0.f};
    acc1[nt] = (f32x4){0.f, 0.f, 0.f, 0.f};
  }

  // layer-1 first half: h (bf16) register-direct from global
#pragma unroll
  for (int ks = 0; ks < 4; ks++) {
    bf16x8 a0 = *(const bf16x8*)(hrow0 + ks * 32 + quad * 8);
    bf16x8 a1 = *(const bf16x8*)(hrow1 + ks * 32 + quad * 8);
#pragma unroll
    for (int nt = 0; nt < 4; nt++) {
      bf16x8 b = W1v[((colG * 4 + nt) * 8 + ks) * 64 + lane];
      acc0[nt] = __builtin_amdgcn_mfma_f32_16x16x32_bf16(b, a0, acc0[nt], 0, 0, 0);
      acc1[nt] = __builtin_amdgcn_mfma_f32_16x16x32_bf16(b, a1, acc1[nt], 0, 0, 0);
    }
  }
  // layer-1 second half: aggregated from LDS
#pragma unroll
  for (int ks2 = 0; ks2 < 4; ks2++) {
    bf16x8 a0 = *(const bf16x8*)&Abuf[tswz(row0, ks2 * 32 + quad * 8)];
    bf16x8 a1 = *(const bf16x8*)&Abuf[tswz(row1, ks2 * 32 + quad * 8)];
#pragma unroll
    for (int nt = 0; nt < 4; nt++) {
      bf16x8 b = W1v[((colG * 4 + nt) * 8 + 4 + ks2) * 64 + lane];
      acc0[nt] = __builtin_amdgcn_mfma_f32_16x16x32_bf16(b, a0, acc0[nt], 0, 0, 0);
      acc1[nt] = __builtin_amdgcn_mfma_f32_16x16x32_bf16(b, a1, acc1[nt], 0, 0, 0);
    }
  }
#pragma unroll
  for (int nt = 0; nt < 4; nt++) {
    int col = colBase + nt * 16 + quad * 4;
    f32x4 bb = *(const f32x4*)&bn1[col];
    bf16x4 o0, o1;
#pragma unroll
    for (int reg = 0; reg < 4; reg++) {
      o0[reg] = (bf16)silu_f(acc0[nt][reg] + bb[reg]);
      o1[reg] = (bf16)silu_f(acc1[nt][reg] + bb[reg]);
    }
    *(bf16x4*)&Tbuf[tswz(row0, col)] = o0;
    *(bf16x4*)&Tbuf[tswz(row1, col)] = o1;
  }
  __syncthreads();   // T complete (both col halves)

#pragma unroll
  for (int nt = 0; nt < 4; nt++) {
    acc0[nt] = (f32x4){0.f, 0.f, 0.f, 0.f};
    acc1[nt] = (f32x4){0.f, 0.f, 0.f, 0.f};
  }
#pragma unroll
  for (int ks = 0; ks < 4; ks++) {
    bf16x8 a0 = *(const bf16x8*)&Tbuf[tswz(row0, ks * 32 + quad * 8)];
    bf16x8 a1 = *(const bf16x8*)&Tbuf[tswz(row1, ks * 32 + quad * 8)];
#pragma unroll
    for (int nt = 0; nt < 4; nt++) {
      bf16x8 b = W2v[((colG * 4 + nt) * 4 + ks) * 64 + lane];
      acc0[nt] = __builtin_amdgcn_mfma_f32_16x16x32_bf16(b, a0, acc0[nt], 0, 0, 0);
      acc1[nt] = __builtin_amdgcn_mfma_f32_16x16x32_bf16(b, a1, acc1[nt], 0, 0, 0);
    }
  }
#pragma unroll
  for (int nt = 0; nt < 4; nt++) {
    int col = colBase + nt * 16 + quad * 4;
    f32x4 bb = *(const f32x4*)&bn2[col];
    f32x4 hv0 = *(const f32x4*)&h[RgA0 * H + col];
    f32x4 hv1 = *(const f32x4*)&h[RgA1 * H + col];
    f32x4 o0, o1;
#pragma unroll
    for (int reg = 0; reg < 4; reg++) {
      o0[reg] = hv0[reg] + acc0[nt][reg] + bb[reg];
      o1[reg] = hv1[reg] + acc1[nt][reg] + bb[reg];
    }
    *(f32x4*)&hout[RgA0 * H + col] = o0;
    *(f32x4*)&hout[RgA1 * H + col] = o1;
  }
}

extern "C" void kernel_launch(void* const* d_in, const int* in_sizes, int n_in,
                              void* d_out, int out_size, void* d_ws,
                              size_t ws_size, hipStream_t stream) {
  const float* h    = (const float*)d_in[0];
  const float* x    = (const float*)d_in[1];
  const int*  bonds = (const int*)d_in[2];
  const float* Wm1  = (const float*)d_in[3];
  const float* bm1  = (const float*)d_in[4];
  const float* Wm2  = (const float*)d_in[5];
  const float* bm2  = (const float*)d_in[6];
  const float* Wn1  = (const float*)d_in[7];
  const float* bn1  = (const float*)d_in[8];
  const float* Wn2  = (const float*)d_in[9];
  const float* bn2  = (const float*)d_in[10];
  const float* Wc1  = (const float*)d_in[11];
  const float* bc1  = (const float*)d_in[12];
  const float* Wc2  = (const float*)d_in[13];

  float* out  = (float*)d_out;
  float* hout = out;
  float* xout = out + (size_t)NBATCH * NA * H;

  char* ws = (char*)d_ws;
  // layout (bytes): NEED = 172,553,216 < 173,080,576 proven available.
  const size_t OFF_DEG  = 0;                        // NA int = 80,000
  const size_t OFF_W1   = 163840;                   // 65,536
  const size_t OFF_W2   = OFF_W1 + 65536;           // 32,768
  const size_t OFF_WN1  = OFF_W2 + 32768;           // 65,536
  const size_t OFF_WN2  = OFF_WN1 + 65536;          // 32,768
  const size_t OFF_WC1  = OFF_WN2 + 32768;          // 32,768 (ends 393,216)
  const size_t OFF_ADJ2 = 393216;                   // NA*32 int = 2,560,000
  const size_t OFF_UPDV = 2953216;                  // NB*8*3 f32 = 5,760,000
  const size_t OFF_HB   = 8713216;                  // 160000*128 bf16 = 40,960,000
  const size_t OFF_MSG  = 49673216;                 // NB*8*128 bf16 = 122,880,000

  int*   degI = (int*)(ws + OFF_DEG);
  bf16*  W1p  = (bf16*)(ws + OFF_W1);
  bf16*  W2p  = (bf16*)(ws + OFF_W2);
  bf16*  Wn1p = (bf16*)(ws + OFF_WN1);
  bf16*  Wn2p = (bf16*)(ws + OFF_WN2);
  bf16*  Wc1p = (bf16*)(ws + OFF_WC1);
  int*   adj2 = (int*)(ws + OFF_ADJ2);
  float* updv = (float*)(ws + OFF_UPDV);
  bf16*  hb   = (bf16*)(ws + OFF_HB);
  bf16*  msgB = (bf16*)(ws + OFF_MSG);

  (void)hipMemsetAsync(degI, 0, NA * sizeof(int), stream);

  prep_kernel<<<PREP_CAST_BLKS + PREP_PACK_BLKS + PREP_ADJ_BLKS, 256, 0,
                stream>>>(h, hb, Wm1, Wm2, Wn1, Wn2, Wc1,
                          W1p, W2p, Wn1p, Wn2p, Wc1p, bonds, degI, adj2);

  msg_kernel<<<NB * NBATCH / 96, 256, 0, stream>>>(
      hb, x, bonds, W1p, bm1, W2p, bm2, Wm1 + 256 * H, Wc1p, bc1, Wc2,
      msgB, updv);
  node_kernel<<<NBATCH * NA / 64, 256, 0, stream>>>(
      h, hb, msgB, updv, degI, adj2, Wn1p, bn1, Wn2p, bn2, x,
      hout, xout);
}

// Round 14
// 431.585 us; speedup vs baseline: 1.0656x; 1.0015x over previous
//
#include <hip/hip_runtime.h>

// BondAwareEGNN fused layer — round 19.
//
// Round-18 post-mortem: msg M=48 only -4us (B-reuse SATURATED, 1:3 ~= 1:2).
// Fresh arithmetic: VALU 36% = ~57us, of which ~2300cyc/thread is 144 silu
// x (exp+rcp, quarter-rate trans) — algorithm-fixed. Occupancy reg-capped
// (r6/r9/r16 all spill). msg near its structural envelope.
//
// Round-19 (scraps, zero risk):
//   1. node: updv side-chain spread across c4 lanes by COMPONENT
//      (c4<3: one coord each, parallel 1-load/edge vs serial 3 on lane0);
//      x_out written per-component.
//   2. msg: msgOut copy hoisted before coord-head MFMAs — 123MB of stores
//      drain under the coord MFMA+silu work.
//   3. All else frozen (msg M=48, prep fusion, node M=32).

#define H      128
#define NA     20000
#define NB     60000
#define NBATCH 8
#define ADJ_CAP 32

typedef __bf16 bf16;
typedef __bf16 bf16x4 __attribute__((ext_vector_type(4)));
typedef __bf16 bf16x8 __attribute__((ext_vector_type(8)));
typedef float  f32x4  __attribute__((ext_vector_type(4)));

__device__ __forceinline__ float silu_f(float v) {
  float e = __expf(-v);
  return v * __builtin_amdgcn_rcpf(1.0f + e);  // 1-ulp rcp; inf -> 0 ok
}

// XOR-swizzled index into a [R][128] bf16 tile. Row stride 256B (bank
// neutral); 16B chunk index XOR'd with row&7 rotates banks. Bijective per
// row; 8-element chunks stay contiguous so bf16x8/bf16x4 ops still work.
__device__ __forceinline__ int tswz(int row, int col) {
  return (row << 7) + (((((col) >> 3) ^ (row & 7)) << 3) | (col & 7));
}

// fp32 KxN(128) row-major -> bf16 fragment-linear (8 bf16 per lane-frag).
__device__ __forceinline__ void pack_one(const float* __restrict__ src,
                                         bf16* __restrict__ dst, int K,
                                         int i) {
  int k = i >> 7, n = i & 127;
  int nt = n >> 4, ks = k >> 5;
  int lane = (((k >> 3) & 3) << 4) | (n & 15);
  int j = k & 7;
  int KS = K >> 5;
  dst[((((nt * KS + ks) * 64) + lane) << 3) + j] = (bf16)src[i];
}

// cast_h (20000 blks) + pack_all (448 blks) + build_adj2 (235 blks) fused.
#define PREP_CAST_BLKS 20000
#define PREP_PACK_BLKS 448
#define PREP_ADJ_BLKS  235
__global__ void prep_kernel(const float* __restrict__ h, bf16* __restrict__ hb,
                            const float* __restrict__ Wm1,
                            const float* __restrict__ Wm2,
                            const float* __restrict__ Wn1,
                            const float* __restrict__ Wn2,
                            const float* __restrict__ Wc1,
                            bf16* __restrict__ W1p, bf16* __restrict__ W2p,
                            bf16* __restrict__ Wn1p, bf16* __restrict__ Wn2p,
                            bf16* __restrict__ Wc1p,
                            const int* __restrict__ bonds,
                            int* __restrict__ degI, int* __restrict__ adj2) {
  const int blk = blockIdx.x;
  if (blk < PREP_CAST_BLKS) {
    int i = blk * 256 + threadIdx.x;  // one float4 per thread
    float4 v = *(const float4*)(h + (size_t)i * 4);
    bf16x4 t = {(bf16)v.x, (bf16)v.y, (bf16)v.z, (bf16)v.w};
    *(bf16x4*)(hb + (size_t)i * 4) = t;
  } else if (blk < PREP_CAST_BLKS + PREP_PACK_BLKS) {
    int i = (blk - PREP_CAST_BLKS) * 256 + threadIdx.x;
    if (i < 32768)       pack_one(Wm1, W1p, 256, i);
    else if (i < 49152)  pack_one(Wm2, W2p, 128, i - 32768);
    else if (i < 81920)  pack_one(Wn1, Wn1p, 256, i - 49152);
    else if (i < 98304)  pack_one(Wn2, Wn2p, 128, i - 81920);
    else if (i < 114688) pack_one(Wc1, Wc1p, 128, i - 98304);
  } else {
    int e = (blk - PREP_CAST_BLKS - PREP_PACK_BLKS) * 256 + threadIdx.x;
    if (e < NB) {
      int s = bonds[2 * e], d = bonds[2 * e + 1];
      int p = atomicAdd(&degI[s], 1);
      if (p < ADJ_CAP) adj2[s * ADJ_CAP + p] = (e << 1);      // src: sign -
      p = atomicAdd(&degI[d], 1);
      if (p < ADJ_CAP) adj2[d * ADJ_CAP + p] = (e << 1) | 1;  // dst: sign +
    }
  }
}

// ---------------- message kernel (M=48 x N=64 per wave, swapped MFMA) ----
__global__ __launch_bounds__(256, 4) void msg_kernel(
    const bf16* __restrict__ hb, const float* __restrict__ x,
    const int* __restrict__ bonds,
    const bf16* __restrict__ W1p, const float* __restrict__ bm1,
    const bf16* __restrict__ W2p, const float* __restrict__ bm2,
    const float* __restrict__ w1c,   // Wm1 row 256 (dist row), fp32[128]
    const bf16* __restrict__ Wc1p, const float* __restrict__ bc1,
    const float* __restrict__ Wc2,
    bf16* __restrict__ msgOut, float* __restrict__ updv) {
  // [96][128] swizzled tile: T after layer-1, messages after layer-2.
  __shared__ __align__(16) bf16 Tbuf[96 * 128];
  __shared__ __align__(16) float cds[96 * 3];
  __shared__ __align__(16) float dists[96];
  __shared__ __align__(16) float bm1s[128], bm2s[128], w1cs[128];
  __shared__ __align__(16) float bc1s[128], wc2s[128];
  __shared__ float cwpart[2][96];

  const int tid = threadIdx.x, blk = blockIdx.x;

  if (tid < 96) {
    int Rg = blk * 96 + tid;
    int bond = Rg >> 3, batch = Rg & 7;
    int s = bonds[2 * bond], dn = bonds[2 * bond + 1];
    const float* xs = x + (size_t)(batch * NA + s) * 3;
    const float* xd = x + (size_t)(batch * NA + dn) * 3;
    float c0 = xd[0] - xs[0], c1 = xd[1] - xs[1], c2 = xd[2] - xs[2];
    cds[tid * 3 + 0] = c0; cds[tid * 3 + 1] = c1; cds[tid * 3 + 2] = c2;
    dists[tid] = sqrtf(c0 * c0 + c1 * c1 + c2 * c2);
  }
  if (tid < 128) {
    bm1s[tid] = bm1[tid]; bm2s[tid] = bm2[tid]; w1cs[tid] = w1c[tid];
    bc1s[tid] = bc1[tid]; wc2s[tid] = Wc2[tid];
  }
  __syncthreads();

  const int lane = tid & 63;
  const int quad = lane >> 4, l16 = lane & 15;
  const int wave = tid >> 6;
  const int rowBase = (wave >> 1) * 48;    // 2 row-groups of 48
  const int colG = wave & 1;               // 2 col-groups of 64
  const int colBase = colG * 64;
  const bf16x8* W1v = (const bf16x8*)W1p;
  const bf16x8* W2v = (const bf16x8*)W2p;
  const bf16x8* Wc1v = (const bf16x8*)Wc1p;

  // per-lane A-row metadata, three row sets
  const int row0 = rowBase + l16, row1 = row0 + 16, row2 = row0 + 32;
  const int Rg0 = blk * 96 + row0;
  const int bn0 = Rg0 >> 3, bat0 = Rg0 & 7;
  const bf16* hs0 = hb + (size_t)(bat0 * NA + bonds[2 * bn0]) * H;
  const bf16* hd0 = hb + (size_t)(bat0 * NA + bonds[2 * bn0 + 1]) * H;
  const int Rg1 = Rg0 + 16;
  const int bn1_ = Rg1 >> 3, bat1 = Rg1 & 7;
  const bf16* hs1 = hb + (size_t)(bat1 * NA + bonds[2 * bn1_]) * H;
  const bf16* hd1 = hb + (size_t)(bat1 * NA + bonds[2 * bn1_ + 1]) * H;
  const int Rg2 = Rg0 + 32;
  const int bn2_ = Rg2 >> 3, bat2 = Rg2 & 7;
  const bf16* hs2 = hb + (size_t)(bat2 * NA + bonds[2 * bn2_]) * H;
  const bf16* hd2 = hb + (size_t)(bat2 * NA + bonds[2 * bn2_ + 1]) * H;
  const float dist0 = dists[row0], dist1 = dists[row1], dist2 = dists[row2];

  f32x4 acc0[4], acc1[4], acc2[4];
#pragma unroll
  for (int nt = 0; nt < 4; nt++) {
    acc0[nt] = (f32x4){0.f, 0.f, 0.f, 0.f};
    acc1[nt] = (f32x4){0.f, 0.f, 0.f, 0.f};
    acc2[nt] = (f32x4){0.f, 0.f, 0.f, 0.f};
  }

  // ---- layer 1: K = 256; each B fragment feeds 3 MFMAs ----
#pragma unroll
  for (int ks = 0; ks < 4; ks++) {
    bf16x8 a0 = *(const bf16x8*)(hs0 + ks * 32 + quad * 8);
    bf16x8 a1 = *(const bf16x8*)(hs1 + ks * 32 + quad * 8);
    bf16x8 a2 = *(const bf16x8*)(hs2 + ks * 32 + quad * 8);
#pragma unroll
    for (int nt = 0; nt < 4; nt++) {
      bf16x8 b = W1v[((colG * 4 + nt) * 8 + ks) * 64 + lane];
      acc0[nt] = __builtin_amdgcn_mfma_f32_16x16x32_bf16(b, a0, acc0[nt], 0, 0, 0);
      acc1[nt] = __builtin_amdgcn_mfma_f32_16x16x32_bf16(b, a1, acc1[nt], 0, 0, 0);
      acc2[nt] = __builtin_amdgcn_mfma_f32_16x16x32_bf16(b, a2, acc2[nt], 0, 0, 0);
    }
  }
#pragma unroll
  for (int ks = 4; ks < 8; ks++) {
    bf16x8 a0 = *(const bf16x8*)(hd0 + (ks - 4) * 32 + quad * 8);
    bf16x8 a1 = *(const bf16x8*)(hd1 + (ks - 4) * 32 + quad * 8);
    bf16x8 a2 = *(const bf16x8*)(hd2 + (ks - 4) * 32 + quad * 8);
#pragma unroll
    for (int nt = 0; nt < 4; nt++) {
      bf16x8 b = W1v[((colG * 4 + nt) * 8 + ks) * 64 + lane];
      acc0[nt] = __builtin_amdgcn_mfma_f32_16x16x32_bf16(b, a0, acc0[nt], 0, 0, 0);
      acc1[nt] = __builtin_amdgcn_mfma_f32_16x16x32_bf16(b, a1, acc1[nt], 0, 0, 0);
      acc2[nt] = __builtin_amdgcn_mfma_f32_16x16x32_bf16(b, a2, acc2[nt], 0, 0, 0);
    }
  }
  // t1 epilogue -> Tbuf: one bf16x4 8B write per tile per row-set
#pragma unroll
  for (int nt = 0; nt < 4; nt++) {
    int col = colBase + nt * 16 + quad * 4;
    f32x4 bb = *(const f32x4*)&bm1s[col];
    f32x4 wc = *(const f32x4*)&w1cs[col];
    bf16x4 o0, o1, o2;
#pragma unroll
    for (int reg = 0; reg < 4; reg++) {
      o0[reg] = (bf16)silu_f(acc0[nt][reg] + bb[reg] + dist0 * wc[reg]);
      o1[reg] = (bf16)silu_f(acc1[nt][reg] + bb[reg] + dist1 * wc[reg]);
      o2[reg] = (bf16)silu_f(acc2[nt][reg] + bb[reg] + dist2 * wc[reg]);
    }
    *(bf16x4*)&Tbuf[tswz(row0, col)] = o0;
    *(bf16x4*)&Tbuf[tswz(row1, col)] = o1;
    *(bf16x4*)&Tbuf[tswz(row2, col)] = o2;
  }
  __syncthreads();   // T complete

  // ---- layer 2: K = 128 -> messages ----
#pragma unroll
  for (int nt = 0; nt < 4; nt++) {
    acc0[nt] = (f32x4){0.f, 0.f, 0.f, 0.f};
    acc1[nt] = (f32x4){0.f, 0.f, 0.f, 0.f};
    acc2[nt] = (f32x4){0.f, 0.f, 0.f, 0.f};
  }
#pragma unroll
  for (int ks = 0; ks < 4; ks++) {
    bf16x8 a0 = *(const bf16x8*)&Tbuf[tswz(row0, ks * 32 + quad * 8)];
    bf16x8 a1 = *(const bf16x8*)&Tbuf[tswz(row1, ks * 32 + quad * 8)];
    bf16x8 a2 = *(const bf16x8*)&Tbuf[tswz(row2, ks * 32 + quad * 8)];
#pragma unroll
    for (int nt = 0; nt < 4; nt++) {
      bf16x8 b = W2v[((colG * 4 + nt) * 4 + ks) * 64 + lane];
      acc0[nt] = __builtin_amdgcn_mfma_f32_16x16x32_bf16(b, a0, acc0[nt], 0, 0, 0);
      acc1[nt] = __builtin_amdgcn_mfma_f32_16x16x32_bf16(b, a1, acc1[nt], 0, 0, 0);
      acc2[nt] = __builtin_amdgcn_mfma_f32_16x16x32_bf16(b, a2, acc2[nt], 0, 0, 0);
    }
  }
  __syncthreads();   // all T reads done; safe to overwrite
#pragma unroll
  for (int nt = 0; nt < 4; nt++) {
    int col = colBase + nt * 16 + quad * 4;
    f32x4 bb = *(const f32x4*)&bm2s[col];
    bf16x4 o0, o1, o2;
#pragma unroll
    for (int reg = 0; reg < 4; reg++) {
      o0[reg] = (bf16)silu_f(acc0[nt][reg] + bb[reg]);
      o1[reg] = (bf16)silu_f(acc1[nt][reg] + bb[reg]);
      o2[reg] = (bf16)silu_f(acc2[nt][reg] + bb[reg]);
    }
    *(bf16x4*)&Tbuf[tswz(row0, col)] = o0;
    *(bf16x4*)&Tbuf[tswz(row1, col)] = o1;
    *(bf16x4*)&Tbuf[tswz(row2, col)] = o2;
  }
  __syncthreads();   // messages complete

  // msgOut copy FIRST: 123MB of stores drain under the coord-head MFMAs.
  // (Reads rows outside this wave's set — barrier above makes that safe.)
#pragma unroll
  for (int i = 0; i < 6; i++) {
    int item = i * 256 + tid;
    int row = item >> 4, cg = item & 15;
    *(bf16x8*)&msgOut[(size_t)(blk * 96 + row) * H + cg * 8] =
        *(const bf16x8*)&Tbuf[tswz(row, cg * 8)];
  }

  // ---- coord head ----
#pragma unroll
  for (int nt = 0; nt < 4; nt++) {
    acc0[nt] = (f32x4){0.f, 0.f, 0.f, 0.f};
    acc1[nt] = (f32x4){0.f, 0.f, 0.f, 0.f};
    acc2[nt] = (f32x4){0.f, 0.f, 0.f, 0.f};
  }
#pragma unroll
  for (int ks = 0; ks < 4; ks++) {
    bf16x8 a0 = *(const bf16x8*)&Tbuf[tswz(row0, ks * 32 + quad * 8)];
    bf16x8 a1 = *(const bf16x8*)&Tbuf[tswz(row1, ks * 32 + quad * 8)];
    bf16x8 a2 = *(const bf16x8*)&Tbuf[tswz(row2, ks * 32 + quad * 8)];
#pragma unroll
    for (int nt = 0; nt < 4; nt++) {
      bf16x8 b = Wc1v[((colG * 4 + nt) * 4 + ks) * 64 + lane];
      acc0[nt] = __builtin_amdgcn_mfma_f32_16x16x32_bf16(b, a0, acc0[nt], 0, 0, 0);
      acc1[nt] = __builtin_amdgcn_mfma_f32_16x16x32_bf16(b, a1, acc1[nt], 0, 0, 0);
      acc2[nt] = __builtin_amdgcn_mfma_f32_16x16x32_bf16(b, a2, acc2[nt], 0, 0, 0);
    }
  }

  // lane-local sum over this lane's 16 cols, then reduce across quads
  float s0 = 0.f, s1 = 0.f, s2 = 0.f;
#pragma unroll
  for (int nt = 0; nt < 4; nt++) {
    int col = colBase + nt * 16 + quad * 4;
    f32x4 bb = *(const f32x4*)&bc1s[col];
    f32x4 w2 = *(const f32x4*)&wc2s[col];
#pragma unroll
    for (int reg = 0; reg < 4; reg++) {
      s0 += silu_f(acc0[nt][reg] + bb[reg]) * w2[reg];
      s1 += silu_f(acc1[nt][reg] + bb[reg]) * w2[reg];
      s2 += silu_f(acc2[nt][reg] + bb[reg]) * w2[reg];
    }
  }
  s0 += __shfl_xor(s0, 16); s0 += __shfl_xor(s0, 32);
  s1 += __shfl_xor(s1, 16); s1 += __shfl_xor(s1, 32);
  s2 += __shfl_xor(s2, 16); s2 += __shfl_xor(s2, 32);
  if (quad == 0) {
    cwpart[colG][row0] = s0;
    cwpart[colG][row1] = s1;
    cwpart[colG][row2] = s2;
  }
  __syncthreads();   // both col-halves' partials in
  if (colG == 0 && quad == 0) {
#pragma unroll
    for (int rs = 0; rs < 3; rs++) {
      int row = row0 + rs * 16;
      size_t Rg = (size_t)blk * 96 + row;
      float cw = cwpart[0][row] + cwpart[1][row];
      float inv = 1.0f / (dists[row] + 1e-8f);
#pragma unroll
      for (int c = 0; c < 3; c++)
        updv[Rg * 3 + c] = cds[row * 3 + c] * inv * cw;
    }
  }
}

// ---------------- node kernel (64 rows; M=32 x N=64 phase-2) --------------
// Phase 1: thread = (row, 64B chunk): 4 threads/row, 2-way unrolled bond
// walk. updv gather spread by COMPONENT across lanes c4<3 (parallel
// 1-load/edge each vs serial 3 on one lane); x_out written per-component.
// Phase 2: 4 waves, each 32 rows x 64 cols (1:2 B:MFMA).
__global__ __launch_bounds__(256, 4) void node_kernel(
    const float* __restrict__ h, const bf16* __restrict__ hb,
    const bf16* __restrict__ msg, const float* __restrict__ updv,
    const int* __restrict__ degI, const int* __restrict__ adj2,
    const bf16* __restrict__ Wn1p, const float* __restrict__ bn1,
    const bf16* __restrict__ Wn2p, const float* __restrict__ bn2,
    const float* __restrict__ x,
    float* __restrict__ hout, float* __restrict__ xout) {
  __shared__ __align__(16) bf16 Abuf[64 * 128];
  __shared__ __align__(16) bf16 Tbuf[64 * 128];

  const int tid = threadIdx.x, blk = blockIdx.x;

  // ---- phase 1: gather (64 rows x 4 chunks of 64B) ----
  {
    const int row = tid >> 2, c4 = tid & 3;
    const int Rg = blk * 64 + row;                // batch*NA + atom
    const int atomA = Rg % NA, batA = Rg / NA;
    int deg = degI[atomA];
    if (deg > ADJ_CAP) deg = ADJ_CAP;
    const int* ap = adj2 + atomA * ADJ_CAP;
    float a32[32];
#pragma unroll
    for (int t = 0; t < 32; t++) a32[t] = 0.f;
    float su = 0.f;           // this lane's coord component (c4 < 3)
    int j = 0;
    for (; j + 2 <= deg; j += 2) {
      int2 e2 = *(const int2*)&ap[j];
      const bf16* m0 = msg + ((size_t)(e2.x >> 1) * 8 + batA) * H + c4 * 32;
      const bf16* m1 = msg + ((size_t)(e2.y >> 1) * 8 + batA) * H + c4 * 32;
      bf16x8 v0 = *(const bf16x8*)(m0),      v1 = *(const bf16x8*)(m0 + 8);
      bf16x8 v2 = *(const bf16x8*)(m0 + 16), v3 = *(const bf16x8*)(m0 + 24);
      bf16x8 u0 = *(const bf16x8*)(m1),      u1 = *(const bf16x8*)(m1 + 8);
      bf16x8 u2 = *(const bf16x8*)(m1 + 16), u3 = *(const bf16x8*)(m1 + 24);
      if (c4 < 3) {
        float sg0 = (e2.x & 1) ? 1.0f : -1.0f;
        float sg1 = (e2.y & 1) ? 1.0f : -1.0f;
        su += sg0 * updv[((size_t)(e2.x >> 1) * 8 + batA) * 3 + c4] +
              sg1 * updv[((size_t)(e2.y >> 1) * 8 + batA) * 3 + c4];
      }
#pragma unroll
      for (int t = 0; t < 8; t++) {
        a32[t]      += (float)v0[t] + (float)u0[t];
        a32[8 + t]  += (float)v1[t] + (float)u1[t];
        a32[16 + t] += (float)v2[t] + (float)u2[t];
        a32[24 + t] += (float)v3[t] + (float)u3[t];
      }
    }
    if (j < deg) {
      int ent0 = ap[j];
      const bf16* m0 = msg + ((size_t)(ent0 >> 1) * 8 + batA) * H + c4 * 32;
      if (c4 < 3) {
        float sg0 = (ent0 & 1) ? 1.0f : -1.0f;
        su += sg0 * updv[((size_t)(ent0 >> 1) * 8 + batA) * 3 + c4];
      }
#pragma unroll
      for (int k = 0; k < 4; k++) {
        bf16x8 v = *(const bf16x8*)(m0 + 8 * k);
#pragma unroll
        for (int t = 0; t < 8; t++) a32[8 * k + t] += (float)v[t];
      }
    }
    if (c4 < 3) {   // x finalize, one component per lane
      float cnt = deg < 1 ? 1.0f : (float)deg;
      size_t o = (size_t)Rg * 3 + c4;
      xout[o] = x[o] + su * __builtin_amdgcn_rcpf(cnt);
    }
#pragma unroll
    for (int k = 0; k < 4; k++) {
      bf16x8 w;
#pragma unroll
      for (int t = 0; t < 8; t++) w[t] = (bf16)a32[8 * k + t];
      *(bf16x8*)&Abuf[tswz(row, c4 * 32 + 8 * k)] = w;
    }
  }
  __syncthreads();   // agg tile ready

  // ---- phase 2: node MLP, M=32 x N=64 per wave, swapped MFMA ----
  const int lane = tid & 63, wave = tid >> 6;
  const int quad = lane >> 4, l16 = lane & 15;
  const int rowBase = (wave >> 1) * 32, colG = wave & 1, colBase = colG * 64;
  const int row0 = rowBase + l16, row1 = row0 + 16;
  const size_t RgA0 = (size_t)blk * 64 + row0;
  const size_t RgA1 = RgA0 + 16;
  const bf16* hrow0 = hb + RgA0 * H;
  const bf16* hrow1 = hb + RgA1 * H;
  const bf16x8* W1v = (const bf16x8*)Wn1p;
  const bf16x8* W2v = (const bf16x8*)Wn2p;

  f32x4 acc0[4], acc1[4];
#pragma unroll
  for (int nt = 0; nt < 4; nt++) {
    acc0[nt] = (f32x4){0.f, 0.f, 0.f, 0.f};
    acc1[nt] = (f32x4){0.f, 0.f, 0.f, 0.f};
  }

  // layer-1 first half: h (bf16) register-direct from global
#pragma unroll
  for (int ks = 0; ks < 4; ks++) {
    bf16x8 a0 = *(const bf16x8*)(hrow0 + ks * 32 + quad * 8);
    bf16x8 a1 = *(const bf16x8*)(hrow1 + ks * 32 + quad * 8);
#pragma unroll
    for (int nt = 0; nt < 4; nt++) {
      bf16x8 b = W1v[((colG * 4 + nt) * 8 + ks) * 64 + lane];
      acc0[nt] = __builtin_amdgcn_mfma_f32_16x16x32_bf16(b, a0, acc0[nt], 0, 0, 0);
      acc1[nt] = __builtin_amdgcn_mfma_f32_16x16x32_bf16(b, a1, acc1[nt], 0, 0, 0);
    }
  }
  // layer-1 second half: aggregated from LDS
#pragma unroll
  for (int ks2 = 0; ks2 < 4; ks2++) {
    bf16x8 a0 = *(const bf16x8*)&Abuf[tswz(row0, ks2 * 32 + quad * 8)];
    bf16x8 a1 = *(const bf16x8*)&Abuf[tswz(row1, ks2 * 32 + quad * 8)];
#pragma unroll
    for (int nt = 0; nt < 4; nt++) {
      bf16x8 b = W1v[((colG * 4 + nt) * 8 + 4 + ks2) * 64 + lane];
      acc0[nt] = __builtin_amdgcn_mfma_f32_16x16x32_bf16(b, a0, acc0[nt], 0, 0, 0);
      acc1[nt] = __builtin_amdgcn_mfma_f32_16x16x32_bf16(b, a1, acc1[nt], 0, 0, 0);
    }
  }
#pragma unroll
  for (int nt = 0; nt < 4; nt++) {
    int col = colBase + nt * 16 + quad * 4;
    f32x4 bb = *(const f32x4*)&bn1[col];
    bf16x4 o0, o1;
#pragma unroll
    for (int reg = 0; reg < 4; reg++) {
      o0[reg] = (bf16)silu_f(acc0[nt][reg] + bb[reg]);
      o1[reg] = (bf16)silu_f(acc1[nt][reg] + bb[reg]);
    }
    *(bf16x4*)&Tbuf[tswz(row0, col)] = o0;
    *(bf16x4*)&Tbuf[tswz(row1, col)] = o1;
  }
  __syncthreads();   // T complete (both col halves)

#pragma unroll
  for (int nt = 0; nt < 4; nt++) {
    acc0[nt] = (f32x4){0.f, 0.f, 0.f, 0.f};
    acc1[nt] = (f32x4){0.f, 0.f, 0.f, 0.f};
  }
#pragma unroll
  for (int ks = 0; ks < 4; ks++) {
    bf16x8 a0 = *(const bf16x8*)&Tbuf[tswz(row0, ks * 32 + quad * 8)];
    bf16x8 a1 = *(const bf16x8*)&Tbuf[tswz(row1, ks * 32 + quad * 8)];
#pragma unroll
    for (int nt = 0; nt < 4; nt++) {
      bf16x8 b = W2v[((colG * 4 + nt) * 4 + ks) * 64 + lane];
      acc0[nt] = __builtin_amdgcn_mfma_f32_16x16x32_bf16(b, a0, acc0[nt], 0, 0, 0);
      acc1[nt] = __builtin_amdgcn_mfma_f32_16x16x32_bf16(b, a1, acc1[nt], 0, 0, 0);
    }
  }
#pragma unroll
  for (int nt = 0; nt < 4; nt++) {
    int col = colBase + nt * 16 + quad * 4;
    f32x4 bb = *(const f32x4*)&bn2[col];
    f32x4 hv0 = *(const f32x4*)&h[RgA0 * H + col];
    f32x4 hv1 = *(const f32x4*)&h[RgA1 * H + col];
    f32x4 o0, o1;
#pragma unroll
    for (int reg = 0; reg < 4; reg++) {
      o0[reg] = hv0[reg] + acc0[nt][reg] + bb[reg];
      o1[reg] = hv1[reg] + acc1[nt][reg] + bb[reg];
    }
    *(f32x4*)&hout[RgA0 * H + col] = o0;
    *(f32x4*)&hout[RgA1 * H + col] = o1;
  }
}

extern "C" void kernel_launch(void* const* d_in, const int* in_sizes, int n_in,
                              void* d_out, int out_size, void* d_ws,
                              size_t ws_size, hipStream_t stream) {
  const float* h    = (const float*)d_in[0];
  const float* x    = (const float*)d_in[1];
  const int*  bonds = (const int*)d_in[2];
  const float* Wm1  = (const float*)d_in[3];
  const float* bm1  = (const float*)d_in[4];
  const float* Wm2  = (const float*)d_in[5];
  const float* bm2  = (const float*)d_in[6];
  const float* Wn1  = (const float*)d_in[7];
  const float* bn1  = (const float*)d_in[8];
  const float* Wn2  = (const float*)d_in[9];
  const float* bn2  = (const float*)d_in[10];
  const float* Wc1  = (const float*)d_in[11];
  const float* bc1  = (const float*)d_in[12];
  const float* Wc2  = (const float*)d_in[13];

  float* out  = (float*)d_out;
  float* hout = out;
  float* xout = out + (size_t)NBATCH * NA * H;

  char* ws = (char*)d_ws;
  // layout (bytes): NEED = 172,553,216 < 173,080,576 proven available.
  const size_t OFF_DEG  = 0;                        // NA int = 80,000
  const size_t OFF_W1   = 163840;                   // 65,536
  const size_t OFF_W2   = OFF_W1 + 65536;           // 32,768
  const size_t OFF_WN1  = OFF_W2 + 32768;           // 65,536
  const size_t OFF_WN2  = OFF_WN1 + 65536;          // 32,768
  const size_t OFF_WC1  = OFF_WN2 + 32768;          // 32,768 (ends 393,216)
  const size_t OFF_ADJ2 = 393216;                   // NA*32 int = 2,560,000
  const size_t OFF_UPDV = 2953216;                  // NB*8*3 f32 = 5,760,000
  const size_t OFF_HB   = 8713216;                  // 160000*128 bf16 = 40,960,000
  const size_t OFF_MSG  = 49673216;                 // NB*8*128 bf16 = 122,880,000

  int*   degI = (int*)(ws + OFF_DEG);
  bf16*  W1p  = (bf16*)(ws + OFF_W1);
  bf16*  W2p  = (bf16*)(ws + OFF_W2);
  bf16*  Wn1p = (bf16*)(ws + OFF_WN1);
  bf16*  Wn2p = (bf16*)(ws + OFF_WN2);
  bf16*  Wc1p = (bf16*)(ws + OFF_WC1);
  int*   adj2 = (int*)(ws + OFF_ADJ2);
  float* updv = (float*)(ws + OFF_UPDV);
  bf16*  hb   = (bf16*)(ws + OFF_HB);
  bf16*  msgB = (bf16*)(ws + OFF_MSG);

  (void)hipMemsetAsync(degI, 0, NA * sizeof(int), stream);

  prep_kernel<<<PREP_CAST_BLKS + PREP_PACK_BLKS + PREP_ADJ_BLKS, 256, 0,
                stream>>>(h, hb, Wm1, Wm2, Wn1, Wn2, Wc1,
                          W1p, W2p, Wn1p, Wn2p, Wc1p, bonds, degI, adj2);

  msg_kernel<<<NB * NBATCH / 96, 256, 0, stream>>>(
      hb, x, bonds, W1p, bm1, W2p, bm2, Wm1 + 256 * H, Wc1p, bc1, Wc2,
      msgB, updv);
  node_kernel<<<NBATCH * NA / 64, 256, 0, stream>>>(
      h, hb, msgB, updv, degI, adj2, Wn1p, bn1, Wn2p, bn2, x,
      hout, xout);
}